// Round 3
// baseline (3613.198 us; speedup 1.0000x reference)
//
#include <hip/hip_runtime.h>
#include <hip/hip_bf16.h>

// DGCNN_Seg forward. B=2, N=4096, K=20. Inputs/outputs fp32 (per reference file).
// Round 2: identical pipeline to round 1, but ALL dtypes fp32 (round 0/1 read
// fp32 buffers as bf16 -> NaN from garbage exponent patterns).

#define DEVI static __device__ __forceinline__

DEVI float lrelu(float y) { return y > 0.f ? y : 0.2f * y; }
// order-preserving float->uint key (monotone): larger float => larger key
DEVI unsigned okey(float f) {
  unsigned u = __float_as_uint(f);
  return (f < 0.f) ? ~u : (u | 0x80000000u);
}
DEVI float dekey(unsigned k) {
  return __uint_as_float((k & 0x80000000u) ? (k & 0x7fffffffu) : ~k);
}

// ---------------- row squared-norms: one wave per row, 8192 rows ----------------
__global__ __launch_bounds__(256) void k_xx(const float* __restrict__ F, int ldf, int C,
                                            float* __restrict__ xx) {
  int lane = threadIdx.x & 63;
  int row = blockIdx.x * 4 + (threadIdx.x >> 6);
  const float* f = F + (size_t)row * ldf;
  float s = 0.f;
  for (int c = lane; c < C; c += 64) { float v = f[c]; s += v * v; }
#pragma unroll
  for (int off = 32; off; off >>= 1) s += __shfl_xor(s, off, 64);
  if (lane == 0) xx[row] = s;
}

// ---------------- pairwise distances, 1024-row chunk of one batch ----------------
// D[(i-ibase), j] = xx_i + xx_j - 2 A A^T ; grid (16,64), block 256, 64x64 tile
__global__ __launch_bounds__(256) void k_dist(const float* __restrict__ F, int ldf, int C,
                                              const float* __restrict__ xx,
                                              float* __restrict__ D, int b, int ibase) {
  __shared__ __align__(16) float As[16][64];
  __shared__ __align__(16) float Bs[16][64];
  const int tid = threadIdx.x;
  const int tx = tid & 15, ty = tid >> 4;
  const int i0 = ibase + blockIdx.x * 64, j0 = blockIdx.y * 64;
  const float* Fb = F + (size_t)b * 4096 * ldf;
  const int row = tid >> 2, q = (tid & 3) * 4;
  float acc[4][4] = {};
  for (int c0 = 0; c0 < C; c0 += 16) {
    if (C - c0 >= 16) {
      float4 a = *(const float4*)(Fb + (size_t)(i0 + row) * ldf + c0 + q);
      float4 w = *(const float4*)(Fb + (size_t)(j0 + row) * ldf + c0 + q);
      As[q + 0][row] = a.x; As[q + 1][row] = a.y; As[q + 2][row] = a.z; As[q + 3][row] = a.w;
      Bs[q + 0][row] = w.x; Bs[q + 1][row] = w.y; Bs[q + 2][row] = w.z; Bs[q + 3][row] = w.w;
    } else {
#pragma unroll
      for (int e = 0; e < 4; ++e) {
        int c = c0 + q + e;
        As[q + e][row] = (c < C) ? Fb[(size_t)(i0 + row) * ldf + c] : 0.f;
        Bs[q + e][row] = (c < C) ? Fb[(size_t)(j0 + row) * ldf + c] : 0.f;
      }
    }
    __syncthreads();
#pragma unroll
    for (int kk = 0; kk < 16; ++kk) {
      const float4 a4 = *(const float4*)&As[kk][ty * 4];
      const float4 b4 = *(const float4*)&Bs[kk][tx * 4];
      const float av[4] = {a4.x, a4.y, a4.z, a4.w};
      const float bv[4] = {b4.x, b4.y, b4.z, b4.w};
#pragma unroll
      for (int ii = 0; ii < 4; ++ii)
#pragma unroll
        for (int jj = 0; jj < 4; ++jj)
          acc[ii][jj] = fmaf(av[ii], bv[jj], acc[ii][jj]);
    }
    __syncthreads();
  }
  const float* xxb = xx + b * 4096;
#pragma unroll
  for (int ii = 0; ii < 4; ++ii) {
    int i = i0 + ty * 4 + ii;
    float xi = xxb[i];
#pragma unroll
    for (int jj = 0; jj < 4; ++jj) {
      int j = j0 + tx * 4 + jj;
      D[(size_t)(i - ibase) * 4096 + j] = xi + xxb[j] - 2.f * acc[ii][jj];
    }
  }
}

// ---------------- top-20 smallest per row, one wave per row (1024-row chunk) ----------------
// key = (ordered(dist)<<32)|j : unsigned compare == (dist, idx) lexicographic (matches lax.top_k ties)
__global__ __launch_bounds__(256) void k_topk(const float* __restrict__ D,
                                              int* __restrict__ idx, int b, int ibase) {
  const int lane = threadIdx.x & 63;
  const int ir_ = blockIdx.x * 4 + (threadIdx.x >> 6);  // row within chunk
  const int i = ibase + ir_;                            // row within batch
  const float* drow = D + (size_t)ir_ * 4096;
  unsigned long long arr[20];
#pragma unroll
  for (int t = 0; t < 20; ++t) arr[t] = ~0ull;
  for (int j = lane; j < 4096; j += 64) {
    float d = drow[j];
    unsigned long long key = ((unsigned long long)okey(d) << 32) | (unsigned)j;
    if (key < arr[19]) {
#pragma unroll
      for (int t = 19; t > 0; --t) {
        bool sh = key < arr[t - 1];
        unsigned long long cand = sh ? arr[t - 1] : key;
        arr[t] = (cand < arr[t]) ? cand : arr[t];
      }
      arr[0] = (key < arr[0]) ? key : arr[0];
    }
  }
  int* op = idx + ((size_t)b * 4096 + i) * 20;
  for (int r = 0; r < 20; ++r) {
    unsigned long long h = arr[0];
#pragma unroll
    for (int off = 32; off; off >>= 1) {
      unsigned long long o = __shfl_xor(h, off, 64);
      h = (o < h) ? o : h;
    }
    if (lane == 0) op[r] = (int)(h & 0xffffffffull);
    bool pop = (arr[0] == h);
#pragma unroll
    for (int t = 0; t < 19; ++t) arr[t] = pop ? arr[t + 1] : arr[t];
    arr[19] = pop ? ~0ull : arr[19];
  }
}

// ---------------- EdgeConv layer 1 (Cin=3, Cout=64): one wave per point ----------------
__global__ __launch_bounds__(256) void k_edge1(const float* __restrict__ xf,
                                               const float* __restrict__ W1,
                                               const float* __restrict__ s1,
                                               const float* __restrict__ b1,
                                               const int* __restrict__ idx,
                                               float* __restrict__ xcat) {
  const int lane = threadIdx.x & 63;
  const int p = blockIdx.x * 4 + (threadIdx.x >> 6);  // flat point 0..8191
  const int bb = p >> 12;
  float wl[3], wr[3];
#pragma unroll
  for (int c = 0; c < 3; ++c) {
    wl[c] = W1[lane * 6 + c];
    wr[c] = W1[lane * 6 + 3 + c];
  }
  const float s = s1[lane], bi = b1[lane];
  const float* xc = xf + (size_t)p * 3;
  const float x0 = xc[0], x1 = xc[1], x2 = xc[2];
  const float t = x0 * (wr[0] - wl[0]) + x1 * (wr[1] - wl[1]) + x2 * (wr[2] - wl[2]);
  const int* ir = idx + (size_t)p * 20;
  float best = -INFINITY;
  for (int k = 0; k < 20; ++k) {
    int j = ir[k];
    const float* xn = xf + ((size_t)(bb << 12) + j) * 3;
    float y = t + xn[0] * wl[0] + xn[1] * wl[1] + xn[2] * wl[2];
    y = lrelu(y * s + bi);
    best = fmaxf(best, y);
  }
  xcat[(size_t)p * 512 + lane] = best;
}

// ---------------- pointwise GEMM: out[m,o] = epi(A[m,:] . Weff[o,:]) ----------------
// EPI: 0=raw store (T), 1=lrelu(acc*s+b), 2=lrelu((acc+extra[b,o])*s+b), 3=gmax atomic
// wsub>0: Weff[o][c] = W[o][wsub+c] - W[o][c]
template <int EPI>
__global__ __launch_bounds__(256) void k_pw(const float* __restrict__ A, int lda, int K,
                                            const float* __restrict__ W, int ldw, int wsub,
                                            const float* __restrict__ sc,
                                            const float* __restrict__ bi,
                                            const float* __restrict__ extra,
                                            float* __restrict__ out, int ldo,
                                            unsigned* __restrict__ gmax, int Ncols) {
  __shared__ __align__(16) float As[16][64];
  __shared__ __align__(16) float Bs[16][64];
  const int tid = threadIdx.x;
  const int tx = tid & 15, ty = tid >> 4;
  const int i0 = blockIdx.x * 64, o0 = blockIdx.y * 64;
  const int row = tid >> 2, q = (tid & 3) * 4;
  float acc[4][4] = {};
  for (int c0 = 0; c0 < K; c0 += 16) {
    float4 a = *(const float4*)(A + (size_t)(i0 + row) * lda + c0 + q);
    As[q + 0][row] = a.x; As[q + 1][row] = a.y; As[q + 2][row] = a.z; As[q + 3][row] = a.w;
    const float* wp = W + (size_t)(o0 + row) * ldw + c0 + q;
#pragma unroll
    for (int e = 0; e < 4; ++e) {
      float w = wp[e];
      if (wsub) w = wp[wsub + e] - w;
      Bs[q + e][row] = w;
    }
    __syncthreads();
#pragma unroll
    for (int kk = 0; kk < 16; ++kk) {
      const float4 a4 = *(const float4*)&As[kk][ty * 4];
      const float4 b4 = *(const float4*)&Bs[kk][tx * 4];
      const float av[4] = {a4.x, a4.y, a4.z, a4.w};
      const float bv[4] = {b4.x, b4.y, b4.z, b4.w};
#pragma unroll
      for (int ii = 0; ii < 4; ++ii)
#pragma unroll
        for (int jj = 0; jj < 4; ++jj)
          acc[ii][jj] = fmaf(av[ii], bv[jj], acc[ii][jj]);
    }
    __syncthreads();
  }
  const int bidx = i0 >> 12;  // batch (64-row tiles never straddle 4096 boundary)
  if (EPI == 0) {
#pragma unroll
    for (int ii = 0; ii < 4; ++ii)
#pragma unroll
      for (int jj = 0; jj < 4; ++jj)
        out[(size_t)(i0 + ty * 4 + ii) * ldo + o0 + tx * 4 + jj] = acc[ii][jj];
  } else if (EPI == 1 || EPI == 2) {
#pragma unroll
    for (int jj = 0; jj < 4; ++jj) {
      int o = o0 + tx * 4 + jj;
      float s = sc[o], bb = bi[o];
      float ex = (EPI == 2) ? extra[bidx * Ncols + o] : 0.f;
#pragma unroll
      for (int ii = 0; ii < 4; ++ii) {
        float y = lrelu((acc[ii][jj] + ex) * s + bb);
        out[(size_t)(i0 + ty * 4 + ii) * ldo + o] = y;
      }
    }
  } else {  // EPI == 3: per-column max over rows -> atomicMax(ordered key)
    float part[4];
#pragma unroll
    for (int jj = 0; jj < 4; ++jj) {
      int o = o0 + tx * 4 + jj;
      float s = sc[o], bb = bi[o];
      float m = -INFINITY;
#pragma unroll
      for (int ii = 0; ii < 4; ++ii) m = fmaxf(m, lrelu(acc[ii][jj] * s + bb));
      part[jj] = m;
    }
#pragma unroll
    for (int jj = 0; jj < 4; ++jj) As[ty][tx * 4 + jj] = part[jj];
    __syncthreads();
    if (ty == 0) {
#pragma unroll
      for (int jj = 0; jj < 4; ++jj) {
        int col = tx * 4 + jj;
        float m = As[0][col];
#pragma unroll
        for (int r = 1; r < 16; ++r) m = fmaxf(m, As[r][col]);
        atomicMax(&gmax[bidx * Ncols + o0 + col], okey(m));
      }
    }
  }
}

// ---------------- EdgeConv GEMM (layers 2-4): M = B*N*K gathered rows ----------------
// y[(n,k),o] = nbr . Wl[o]; epilogue: lrelu((y + T[n,o])*s+b), max over k-group of 20
// tile 80 rows (4 points) x 64 cols, block 256, thread 5x4
__global__ __launch_bounds__(256) void k_edge(const float* __restrict__ F, int ldf, int Cin,
                                              const float* __restrict__ W,
                                              const float* __restrict__ sc,
                                              const float* __restrict__ bi,
                                              const int* __restrict__ idx,
                                              const float* __restrict__ T, int ldt,
                                              float* __restrict__ out, int ldo) {
  __shared__ float As[16][80];
  __shared__ __align__(16) float Bs[16][64];
  __shared__ float Ys[80][64];
  const int tid = threadIdx.x;
  const int tx = tid & 15, ty = tid >> 4;
  const int r0 = blockIdx.x * 80;  // global edge-row base (aligned to k-groups)
  const int o0 = blockIdx.y * 64;
  const int ldw = 2 * Cin;
  // precompute gathered source rows for this thread's 5 A-elements
  int grow[5], gcol[5];
#pragma unroll
  for (int l = 0; l < 5; ++l) {
    int e = tid + l * 256;
    int rr = e >> 4;
    gcol[l] = e & 15;
    int gr = r0 + rr;
    int p = gr / 20;
    int j = idx[(size_t)p * 20 + (gr % 20)];
    grow[l] = ((p >> 12) << 12) + j;  // b*4096 + j
  }
  float acc[5][4] = {};
  const int wrow = tid >> 2, wq = (tid & 3) * 4;
  for (int c0 = 0; c0 < Cin; c0 += 16) {
#pragma unroll
    for (int l = 0; l < 5; ++l) {
      int e = tid + l * 256;
      As[gcol[l]][e >> 4] = F[(size_t)grow[l] * ldf + c0 + gcol[l]];
    }
    {
      const float* wp = W + (size_t)(o0 + wrow) * ldw + c0 + wq;
#pragma unroll
      for (int e = 0; e < 4; ++e) Bs[wq + e][wrow] = wp[e];
    }
    __syncthreads();
#pragma unroll
    for (int kk = 0; kk < 16; ++kk) {
      float a[5];
#pragma unroll
      for (int l = 0; l < 5; ++l) a[l] = As[kk][ty + l * 16];
      const float4 b4 = *(const float4*)&Bs[kk][tx * 4];
      const float bv[4] = {b4.x, b4.y, b4.z, b4.w};
#pragma unroll
      for (int l = 0; l < 5; ++l)
#pragma unroll
        for (int jj = 0; jj < 4; ++jj)
          acc[l][jj] = fmaf(a[l], bv[jj], acc[l][jj]);
    }
    __syncthreads();
  }
  // epilogue into Ys
#pragma unroll
  for (int l = 0; l < 5; ++l) {
    int r = ty + l * 16;
    int p = (r0 + r) / 20;
#pragma unroll
    for (int jj = 0; jj < 4; ++jj) {
      int o = o0 + tx * 4 + jj;
      float y = (acc[l][jj] + T[(size_t)p * ldt + o]) * sc[o] + bi[o];
      Ys[r][tx * 4 + jj] = lrelu(y);
    }
  }
  __syncthreads();
  // max over 20-row groups: 4 groups x 64 cols = 256 outputs
  const int grp = tid >> 6, col = tid & 63;
  float m = -INFINITY;
#pragma unroll
  for (int k = 0; k < 20; ++k) m = fmaxf(m, Ys[grp * 20 + k][col]);
  const int p = blockIdx.x * 4 + grp;
  out[(size_t)p * ldo + o0 + col] = m;
}

// ---------------- bias2[b][o] = sum_c gmax[b][c] * Ws1[o][512+c] ----------------
__global__ __launch_bounds__(512) void k_bias2(const unsigned* __restrict__ gk,
                                               const float* __restrict__ Ws1,
                                               float* __restrict__ bias2) {
  const int b = blockIdx.x, o = threadIdx.x;
  float acc = 0.f;
  for (int c = 0; c < 1024; ++c)
    acc = fmaf(dekey(gk[b * 1024 + c]), Ws1[(size_t)o * 1536 + 512 + c], acc);
  bias2[b * 512 + o] = acc;
}

// ---------------- final head: out = H(8192x256) . Ws3(13x256)^T + bs3, fp32 store ----------------
__global__ __launch_bounds__(256) void k_out(const float* __restrict__ H,
                                             const float* __restrict__ Ws3,
                                             const float* __restrict__ bs3,
                                             float* __restrict__ out) {
  __shared__ float Ws[13][256];
  const int tid = threadIdx.x;
  for (int e = tid; e < 13 * 256; e += 256) Ws[e >> 8][e & 255] = Ws3[e];
  __syncthreads();
  const int rloc = tid >> 4, o = tid & 15;
  const int row = blockIdx.x * 16 + rloc;
  if (o < 13) {
    const float* h = H + (size_t)row * 256;
    float acc = 0.f;
    for (int c = 0; c < 256; ++c) acc = fmaf(h[c], Ws[o][c], acc);
    out[(size_t)row * 13 + o] = acc + bs3[o];
  }
}

extern "C" void kernel_launch(void* const* d_in, const int* in_sizes, int n_in,
                              void* d_out, int out_size, void* d_ws, size_t ws_size,
                              hipStream_t stream) {
  const float* X   = (const float*)d_in[0];
  const float* W1  = (const float*)d_in[1];
  const float* S1  = (const float*)d_in[2];
  const float* B1  = (const float*)d_in[3];
  const float* W2  = (const float*)d_in[4];
  const float* S2  = (const float*)d_in[5];
  const float* B2  = (const float*)d_in[6];
  const float* W3  = (const float*)d_in[7];
  const float* S3  = (const float*)d_in[8];
  const float* B3  = (const float*)d_in[9];
  const float* W4  = (const float*)d_in[10];
  const float* S4  = (const float*)d_in[11];
  const float* B4  = (const float*)d_in[12];
  const float* Wg  = (const float*)d_in[13];
  const float* Sg  = (const float*)d_in[14];
  const float* Bg  = (const float*)d_in[15];
  const float* Ws1 = (const float*)d_in[16];
  const float* Ss1 = (const float*)d_in[17];
  const float* Bs1 = (const float*)d_in[18];
  const float* Ws2 = (const float*)d_in[19];
  const float* Ss2 = (const float*)d_in[20];
  const float* Bs2 = (const float*)d_in[21];
  const float* Ws3 = (const float*)d_in[22];
  const float* Bs3 = (const float*)d_in[23];

  char* ws = (char*)d_ws;
  // Compact workspace layout, total ~41 MB.
  // Lifetime aliasing: dist (knn phase) overlays Tbuf+h1 (post-knn phase).
  float*    xxb   = (float*)(ws + 0);          //   8192 f
  int*      idxb  = (int*)  (ws + 32768);      // 2*4096*20 int (655360 B)
  unsigned* gk    = (unsigned*)(ws + 688128);  // 2*1024 u32
  float*    b2g   = (float*)(ws + 696320);     // 2*512 f
  float*    xcat  = (float*)(ws + 1048576);    // 8192*512 f (16 MB)
  char*     region = ws + 17825792;            // 24 MB shared region
  float*    dist  = (float*)(region);          // 1024*4096 f (16 MB), knn only
  float*    Tbuf  = (float*)(region);          // 8192*256 f (8 MB), per-layer T & h2
  float*    h1    = (float*)(region + 8388608);// 8192*512 f (16 MB), head only
  // total end: 17825792 + 25165824 = 42991616 bytes

  hipMemsetAsync(gk, 0, 2 * 1024 * sizeof(unsigned), stream);

  // ---- Layer 1 (C=3 -> 64, out xcat[:,0:64]) ----
  k_xx<<<dim3(2048), dim3(256), 0, stream>>>(X, 3, 3, xxb);
  for (int b = 0; b < 2; ++b)
    for (int c = 0; c < 4; ++c) {
      k_dist<<<dim3(16, 64), dim3(256), 0, stream>>>(X, 3, 3, xxb, dist, b, c * 1024);
      k_topk<<<dim3(256), dim3(256), 0, stream>>>(dist, idxb, b, c * 1024);
    }
  k_edge1<<<dim3(2048), dim3(256), 0, stream>>>(X, W1, S1, B1, idxb, xcat);

  // ---- Layer 2 (Cin=64 -> 64, in xcat[:,0:64], out xcat[:,64:128]) ----
  k_xx<<<dim3(2048), dim3(256), 0, stream>>>(xcat, 512, 64, xxb);
  for (int b = 0; b < 2; ++b)
    for (int c = 0; c < 4; ++c) {
      k_dist<<<dim3(16, 64), dim3(256), 0, stream>>>(xcat, 512, 64, xxb, dist, b, c * 1024);
      k_topk<<<dim3(256), dim3(256), 0, stream>>>(dist, idxb, b, c * 1024);
    }
  k_pw<0><<<dim3(128, 1), dim3(256), 0, stream>>>(xcat, 512, 64, W2, 128, 64,
      nullptr, nullptr, nullptr, Tbuf, 64, nullptr, 64);
  k_edge<<<dim3(2048, 1), dim3(256), 0, stream>>>(xcat, 512, 64, W2, S2, B2,
      idxb, Tbuf, 64, xcat + 64, 512);

  // ---- Layer 3 (Cin=64 -> 128, in xcat[:,64:128], out xcat[:,128:256]) ----
  k_xx<<<dim3(2048), dim3(256), 0, stream>>>(xcat + 64, 512, 64, xxb);
  for (int b = 0; b < 2; ++b)
    for (int c = 0; c < 4; ++c) {
      k_dist<<<dim3(16, 64), dim3(256), 0, stream>>>(xcat + 64, 512, 64, xxb, dist, b, c * 1024);
      k_topk<<<dim3(256), dim3(256), 0, stream>>>(dist, idxb, b, c * 1024);
    }
  k_pw<0><<<dim3(128, 2), dim3(256), 0, stream>>>(xcat + 64, 512, 64, W3, 128, 64,
      nullptr, nullptr, nullptr, Tbuf, 128, nullptr, 128);
  k_edge<<<dim3(2048, 2), dim3(256), 0, stream>>>(xcat + 64, 512, 64, W3, S3, B3,
      idxb, Tbuf, 128, xcat + 128, 512);

  // ---- Layer 4 (Cin=128 -> 256, in xcat[:,128:256], out xcat[:,256:512]) ----
  k_xx<<<dim3(2048), dim3(256), 0, stream>>>(xcat + 128, 512, 128, xxb);
  for (int b = 0; b < 2; ++b)
    for (int c = 0; c < 4; ++c) {
      k_dist<<<dim3(16, 64), dim3(256), 0, stream>>>(xcat + 128, 512, 128, xxb, dist, b, c * 1024);
      k_topk<<<dim3(256), dim3(256), 0, stream>>>(dist, idxb, b, c * 1024);
    }
  k_pw<0><<<dim3(128, 4), dim3(256), 0, stream>>>(xcat + 128, 512, 128, W4, 256, 128,
      nullptr, nullptr, nullptr, Tbuf, 256, nullptr, 256);
  k_edge<<<dim3(2048, 4), dim3(256), 0, stream>>>(xcat + 128, 512, 128, W4, S4, B4,
      idxb, Tbuf, 256, xcat + 256, 512);

  // ---- head: gmax -> bias2 -> h1 -> h2 -> logits ----
  k_pw<3><<<dim3(128, 16), dim3(256), 0, stream>>>(xcat, 512, 512, Wg, 512, 0,
      Sg, Bg, nullptr, nullptr, 0, gk, 1024);
  k_bias2<<<dim3(2), dim3(512), 0, stream>>>(gk, Ws1, b2g);
  k_pw<2><<<dim3(128, 8), dim3(256), 0, stream>>>(xcat, 512, 512, Ws1, 1536, 0,
      Ss1, Bs1, b2g, h1, 512, nullptr, 512);
  k_pw<1><<<dim3(128, 4), dim3(256), 0, stream>>>(h1, 512, 512, Ws2, 512, 0,
      Ss2, Bs2, nullptr, Tbuf, 256, nullptr, 256);
  k_out<<<dim3(512), dim3(256), 0, stream>>>(Tbuf, Ws3, Bs3, (float*)d_out);
}

// Round 4
// 2974.957 us; speedup vs baseline: 1.2145x; 1.2145x over previous
//
#include <hip/hip_runtime.h>
#include <hip/hip_bf16.h>

// DGCNN_Seg forward. B=2, N=4096, K=20. fp32 in/out; bf16 MFMA for layer-4 +
// head GEMMs (nothing that feeds kNN), fp32 for kNN-feeding path (layers 1-3).

#define DEVI static __device__ __forceinline__
typedef __attribute__((ext_vector_type(8))) short bf16x8;   // 8 bf16 = 4 VGPR
typedef __attribute__((ext_vector_type(4))) float f32x4;    // MFMA acc

DEVI float lrelu(float y) { return y > 0.f ? y : 0.2f * y; }
DEVI unsigned okey(float f) {
  unsigned u = __float_as_uint(f);
  return (f < 0.f) ? ~u : (u | 0x80000000u);
}
DEVI float dekey(unsigned k) {
  return __uint_as_float((k & 0x80000000u) ? (k & 0x7fffffffu) : ~k);
}

// ---------------- weight fp32 -> bf16 pack: dst[o][c] = src[o*lds+off+c] (- src[o*lds+c] if sub)
__global__ __launch_bounds__(64) void k_conv(const float* __restrict__ src, int lds, int off,
                                             int sub, int Kc, __hip_bfloat16* __restrict__ dst) {
  int o = blockIdx.x, c = blockIdx.y * 64 + threadIdx.x;
  float v = src[(size_t)o * lds + off + c];
  if (sub) v -= src[(size_t)o * lds + c];
  dst[(size_t)o * Kc + c] = __float2bfloat16(v);
}

// ---------------- row squared-norms: one wave per row ----------------
__global__ __launch_bounds__(256) void k_xx(const float* __restrict__ F, int ldf, int C,
                                            float* __restrict__ xx) {
  int lane = threadIdx.x & 63;
  int row = blockIdx.x * 4 + (threadIdx.x >> 6);
  const float* f = F + (size_t)row * ldf;
  float s = 0.f;
  for (int c = lane; c < C; c += 64) { float v = f[c]; s += v * v; }
#pragma unroll
  for (int off = 32; off; off >>= 1) s += __shfl_xor(s, off, 64);
  if (lane == 0) xx[row] = s;
}

// ---------------- pairwise distances, 1024-row chunk (fp32; feeds kNN) ----------------
__global__ __launch_bounds__(256) void k_dist(const float* __restrict__ F, int ldf, int C,
                                              const float* __restrict__ xx,
                                              float* __restrict__ D, int b, int ibase) {
  __shared__ __align__(16) float As[16][64];
  __shared__ __align__(16) float Bs[16][64];
  const int tid = threadIdx.x;
  const int tx = tid & 15, ty = tid >> 4;
  const int i0 = ibase + blockIdx.x * 64, j0 = blockIdx.y * 64;
  const float* Fb = F + (size_t)b * 4096 * ldf;
  const int row = tid >> 2, q = (tid & 3) * 4;
  float acc[4][4] = {};
  for (int c0 = 0; c0 < C; c0 += 16) {
    if (C - c0 >= 16) {
      float4 a = *(const float4*)(Fb + (size_t)(i0 + row) * ldf + c0 + q);
      float4 w = *(const float4*)(Fb + (size_t)(j0 + row) * ldf + c0 + q);
      As[q + 0][row] = a.x; As[q + 1][row] = a.y; As[q + 2][row] = a.z; As[q + 3][row] = a.w;
      Bs[q + 0][row] = w.x; Bs[q + 1][row] = w.y; Bs[q + 2][row] = w.z; Bs[q + 3][row] = w.w;
    } else {
#pragma unroll
      for (int e = 0; e < 4; ++e) {
        int c = c0 + q + e;
        As[q + e][row] = (c < C) ? Fb[(size_t)(i0 + row) * ldf + c] : 0.f;
        Bs[q + e][row] = (c < C) ? Fb[(size_t)(j0 + row) * ldf + c] : 0.f;
      }
    }
    __syncthreads();
#pragma unroll
    for (int kk = 0; kk < 16; ++kk) {
      const float4 a4 = *(const float4*)&As[kk][ty * 4];
      const float4 b4 = *(const float4*)&Bs[kk][tx * 4];
      const float av[4] = {a4.x, a4.y, a4.z, a4.w};
      const float bv[4] = {b4.x, b4.y, b4.z, b4.w};
#pragma unroll
      for (int ii = 0; ii < 4; ++ii)
#pragma unroll
        for (int jj = 0; jj < 4; ++jj)
          acc[ii][jj] = fmaf(av[ii], bv[jj], acc[ii][jj]);
    }
    __syncthreads();
  }
  const float* xxb = xx + b * 4096;
#pragma unroll
  for (int ii = 0; ii < 4; ++ii) {
    int i = i0 + ty * 4 + ii;
    float xi = xxb[i];
#pragma unroll
    for (int jj = 0; jj < 4; ++jj) {
      int j = j0 + tx * 4 + jj;
      D[(size_t)(i - ibase) * 4096 + j] = xi + xxb[j] - 2.f * acc[ii][jj];
    }
  }
}

// ---------------- top-20 smallest per row, one wave per row ----------------
__global__ __launch_bounds__(256) void k_topk(const float* __restrict__ D,
                                              int* __restrict__ idx, int b, int ibase) {
  const int lane = threadIdx.x & 63;
  const int ir_ = blockIdx.x * 4 + (threadIdx.x >> 6);
  const int i = ibase + ir_;
  const float* drow = D + (size_t)ir_ * 4096;
  unsigned long long arr[20];
#pragma unroll
  for (int t = 0; t < 20; ++t) arr[t] = ~0ull;
  for (int j = lane; j < 4096; j += 64) {
    float d = drow[j];
    unsigned long long key = ((unsigned long long)okey(d) << 32) | (unsigned)j;
    if (key < arr[19]) {
#pragma unroll
      for (int t = 19; t > 0; --t) {
        bool sh = key < arr[t - 1];
        unsigned long long cand = sh ? arr[t - 1] : key;
        arr[t] = (cand < arr[t]) ? cand : arr[t];
      }
      arr[0] = (key < arr[0]) ? key : arr[0];
    }
  }
  int* op = idx + ((size_t)b * 4096 + i) * 20;
  for (int r = 0; r < 20; ++r) {
    unsigned long long h = arr[0];
#pragma unroll
    for (int off = 32; off; off >>= 1) {
      unsigned long long o = __shfl_xor(h, off, 64);
      h = (o < h) ? o : h;
    }
    if (lane == 0) op[r] = (int)(h & 0xffffffffull);
    bool pop = (arr[0] == h);
#pragma unroll
    for (int t = 0; t < 19; ++t) arr[t] = pop ? arr[t + 1] : arr[t];
    arr[19] = pop ? ~0ull : arr[19];
  }
}

// ---------------- EdgeConv layer 1 (fp32, Cin=3): one wave per point ----------------
__global__ __launch_bounds__(256) void k_edge1(const float* __restrict__ xf,
                                               const float* __restrict__ W1,
                                               const float* __restrict__ s1,
                                               const float* __restrict__ b1,
                                               const int* __restrict__ idx,
                                               float* __restrict__ xcat,
                                               __hip_bfloat16* __restrict__ xcatb) {
  const int lane = threadIdx.x & 63;
  const int p = blockIdx.x * 4 + (threadIdx.x >> 6);
  const int bb = p >> 12;
  float wl[3], wr[3];
#pragma unroll
  for (int c = 0; c < 3; ++c) {
    wl[c] = W1[lane * 6 + c];
    wr[c] = W1[lane * 6 + 3 + c];
  }
  const float s = s1[lane], bi = b1[lane];
  const float* xc = xf + (size_t)p * 3;
  const float x0 = xc[0], x1 = xc[1], x2 = xc[2];
  const float t = x0 * (wr[0] - wl[0]) + x1 * (wr[1] - wl[1]) + x2 * (wr[2] - wl[2]);
  const int* ir = idx + (size_t)p * 20;
  float best = -INFINITY;
  for (int k = 0; k < 20; ++k) {
    int j = ir[k];
    const float* xn = xf + ((size_t)(bb << 12) + j) * 3;
    float y = t + xn[0] * wl[0] + xn[1] * wl[1] + xn[2] * wl[2];
    y = lrelu(y * s + bi);
    best = fmaxf(best, y);
  }
  xcat[(size_t)p * 512 + lane] = best;
  xcatb[(size_t)p * 512 + lane] = __float2bfloat16(best);
}

// ---------------- fp32 pointwise GEMM, raw store (T for layers 2-3) ----------------
__global__ __launch_bounds__(256) void k_pwT(const float* __restrict__ A, int lda, int K,
                                             const float* __restrict__ W, int ldw, int wsub,
                                             float* __restrict__ out, int ldo) {
  __shared__ __align__(16) float As[16][64];
  __shared__ __align__(16) float Bs[16][64];
  const int tid = threadIdx.x;
  const int tx = tid & 15, ty = tid >> 4;
  const int i0 = blockIdx.x * 64, o0 = blockIdx.y * 64;
  const int row = tid >> 2, q = (tid & 3) * 4;
  float acc[4][4] = {};
  for (int c0 = 0; c0 < K; c0 += 16) {
    float4 a = *(const float4*)(A + (size_t)(i0 + row) * lda + c0 + q);
    As[q + 0][row] = a.x; As[q + 1][row] = a.y; As[q + 2][row] = a.z; As[q + 3][row] = a.w;
    const float* wp = W + (size_t)(o0 + row) * ldw + c0 + q;
#pragma unroll
    for (int e = 0; e < 4; ++e) Bs[q + e][row] = wp[wsub + e] - wp[e];
    __syncthreads();
#pragma unroll
    for (int kk = 0; kk < 16; ++kk) {
      const float4 a4 = *(const float4*)&As[kk][ty * 4];
      const float4 b4 = *(const float4*)&Bs[kk][tx * 4];
      const float av[4] = {a4.x, a4.y, a4.z, a4.w};
      const float bv[4] = {b4.x, b4.y, b4.z, b4.w};
#pragma unroll
      for (int ii = 0; ii < 4; ++ii)
#pragma unroll
        for (int jj = 0; jj < 4; ++jj)
          acc[ii][jj] = fmaf(av[ii], bv[jj], acc[ii][jj]);
    }
    __syncthreads();
  }
#pragma unroll
  for (int ii = 0; ii < 4; ++ii)
#pragma unroll
    for (int jj = 0; jj < 4; ++jj)
      out[(size_t)(i0 + ty * 4 + ii) * ldo + o0 + tx * 4 + jj] = acc[ii][jj];
}

// ---------------- fp32 EdgeConv GEMM (layers 2-3; feeds kNN, stays exact) ----------------
__global__ __launch_bounds__(256) void k_edge(const float* __restrict__ F, int ldf, int Cin,
                                              const float* __restrict__ W,
                                              const float* __restrict__ sc,
                                              const float* __restrict__ bi,
                                              const int* __restrict__ idx,
                                              const float* __restrict__ T, int ldt,
                                              float* __restrict__ out,
                                              __hip_bfloat16* __restrict__ outb) {
  __shared__ float As[16][80];
  __shared__ __align__(16) float Bs[16][64];
  __shared__ float Ys[80][64];
  const int tid = threadIdx.x;
  const int tx = tid & 15, ty = tid >> 4;
  const int r0 = blockIdx.x * 80;
  const int o0 = blockIdx.y * 64;
  const int ldw = 2 * Cin;
  int grow[5], gcol[5];
#pragma unroll
  for (int l = 0; l < 5; ++l) {
    int e = tid + l * 256;
    int rr = e >> 4;
    gcol[l] = e & 15;
    int gr = r0 + rr;
    int p = gr / 20;
    int j = idx[(size_t)p * 20 + (gr % 20)];
    grow[l] = ((p >> 12) << 12) + j;
  }
  float acc[5][4] = {};
  const int wrow = tid >> 2, wq = (tid & 3) * 4;
  for (int c0 = 0; c0 < Cin; c0 += 16) {
#pragma unroll
    for (int l = 0; l < 5; ++l) {
      int e = tid + l * 256;
      As[gcol[l]][e >> 4] = F[(size_t)grow[l] * ldf + c0 + gcol[l]];
    }
    {
      const float* wp = W + (size_t)(o0 + wrow) * ldw + c0 + wq;
#pragma unroll
      for (int e = 0; e < 4; ++e) Bs[wq + e][wrow] = wp[e];
    }
    __syncthreads();
#pragma unroll
    for (int kk = 0; kk < 16; ++kk) {
      float a[5];
#pragma unroll
      for (int l = 0; l < 5; ++l) a[l] = As[kk][ty + l * 16];
      const float4 b4 = *(const float4*)&Bs[kk][tx * 4];
      const float bv[4] = {b4.x, b4.y, b4.z, b4.w};
#pragma unroll
      for (int l = 0; l < 5; ++l)
#pragma unroll
        for (int jj = 0; jj < 4; ++jj)
          acc[l][jj] = fmaf(a[l], bv[jj], acc[l][jj]);
    }
    __syncthreads();
  }
#pragma unroll
  for (int l = 0; l < 5; ++l) {
    int r = ty + l * 16;
    int p = (r0 + r) / 20;
#pragma unroll
    for (int jj = 0; jj < 4; ++jj) {
      int o = o0 + tx * 4 + jj;
      float y = (acc[l][jj] + T[(size_t)p * ldt + o]) * sc[o] + bi[o];
      Ys[r][tx * 4 + jj] = lrelu(y);
    }
  }
  __syncthreads();
  const int grp = tid >> 6, col = tid & 63;
  float m = -INFINITY;
#pragma unroll
  for (int k = 0; k < 20; ++k) m = fmaxf(m, Ys[grp * 20 + k][col]);
  const int p = blockIdx.x * 4 + grp;
  out[(size_t)p * 512 + o0 + col] = m;
  outb[(size_t)p * 512 + o0 + col] = __float2bfloat16(m);
}

// ---------------- MFMA bf16 GEMM: block 128(M)x64(N), 4 waves x (32x64) ----------------
// EPI: 0=raw fp32 store, 1=lrelu((acc+extra)*s+b) -> outf/outb, 2=per-col max -> gmax atomic
template <int EPI>
__global__ __launch_bounds__(256) void k_mm(
    const __hip_bfloat16* __restrict__ A, int lda, int K,
    const __hip_bfloat16* __restrict__ B,  // [N][K] bf16
    const float* __restrict__ sc, const float* __restrict__ bi,
    const float* __restrict__ extra, int Ncols,
    float* __restrict__ outf, int ldof,
    __hip_bfloat16* __restrict__ outb, int ldob,
    unsigned* __restrict__ gmax) {
  __shared__ __align__(16) __hip_bfloat16 Al[128 * 40];
  __shared__ __align__(16) __hip_bfloat16 Bl[64 * 40];
  __shared__ float Red[4][64];
  const int tid = threadIdx.x, lane = tid & 63, wv = tid >> 6;
  const int m0 = blockIdx.x * 128, n0 = blockIdx.y * 64;
  const int arow = tid >> 2, akc = (tid & 3) * 8;
  const int fm = lane & 15, fq = lane >> 4;
  f32x4 acc[2][4];
#pragma unroll
  for (int mt = 0; mt < 2; ++mt)
#pragma unroll
    for (int nt = 0; nt < 4; ++nt) acc[mt][nt] = (f32x4){0.f, 0.f, 0.f, 0.f};
  for (int c0 = 0; c0 < K; c0 += 32) {
#pragma unroll
    for (int l = 0; l < 2; ++l) {
      int r = arow + l * 64;
      *(float4*)&Al[r * 40 + akc] = *(const float4*)(A + (size_t)(m0 + r) * lda + c0 + akc);
    }
    *(float4*)&Bl[arow * 40 + akc] = *(const float4*)(B + (size_t)(n0 + arow) * K + c0 + akc);
    __syncthreads();
    bf16x8 af[2], bfr[4];
#pragma unroll
    for (int mt = 0; mt < 2; ++mt)
      af[mt] = *(const bf16x8*)&Al[(wv * 32 + mt * 16 + fm) * 40 + fq * 8];
#pragma unroll
    for (int nt = 0; nt < 4; ++nt)
      bfr[nt] = *(const bf16x8*)&Bl[(nt * 16 + fm) * 40 + fq * 8];
#pragma unroll
    for (int mt = 0; mt < 2; ++mt)
#pragma unroll
      for (int nt = 0; nt < 4; ++nt)
        acc[mt][nt] = __builtin_amdgcn_mfma_f32_16x16x32_bf16(af[mt], bfr[nt], acc[mt][nt], 0, 0, 0);
    __syncthreads();
  }
  const int bidx = m0 >> 12;
  if (EPI == 0) {
#pragma unroll
    for (int mt = 0; mt < 2; ++mt)
#pragma unroll
      for (int nt = 0; nt < 4; ++nt)
#pragma unroll
        for (int r = 0; r < 4; ++r)
          outf[(size_t)(m0 + wv * 32 + mt * 16 + fq * 4 + r) * ldof + n0 + nt * 16 + fm] =
              acc[mt][nt][r];
  } else if (EPI == 1) {
#pragma unroll
    for (int nt = 0; nt < 4; ++nt) {
      int col = n0 + nt * 16 + fm;
      float s = sc[col], bb = bi[col];
      float ex = extra ? extra[bidx * Ncols + col] : 0.f;
#pragma unroll
      for (int mt = 0; mt < 2; ++mt)
#pragma unroll
        for (int r = 0; r < 4; ++r) {
          float v = lrelu((acc[mt][nt][r] + ex) * s + bb);
          size_t rr = (size_t)(m0 + wv * 32 + mt * 16 + fq * 4 + r);
          if (outf) outf[rr * ldof + col] = v;
          if (outb) outb[rr * ldob + col] = __float2bfloat16(v);
        }
    }
  } else {
#pragma unroll
    for (int nt = 0; nt < 4; ++nt) {
      int col = n0 + nt * 16 + fm;
      float s = sc[col], bb = bi[col];
      float m = -INFINITY;
#pragma unroll
      for (int mt = 0; mt < 2; ++mt)
#pragma unroll
        for (int r = 0; r < 4; ++r) m = fmaxf(m, lrelu(acc[mt][nt][r] * s + bb));
      m = fmaxf(m, __shfl_xor(m, 16, 64));
      m = fmaxf(m, __shfl_xor(m, 32, 64));
      if (fq == 0) Red[wv][nt * 16 + fm] = m;
    }
    __syncthreads();
    if (tid < 64) {
      float m = fmaxf(fmaxf(Red[0][tid], Red[1][tid]), fmaxf(Red[2][tid], Red[3][tid]));
      atomicMax(&gmax[bidx * Ncols + n0 + tid], okey(m));
    }
  }
}

// ---------------- MFMA bf16 EdgeConv (layer 4): 320 edges x 64 cols / block ----------------
// out[p][o] = lrelu((max_k(nbr_k . Wl[o]) + T[p][o]) * s[o] + b[o])  (s>0, lrelu monotone)
__global__ __launch_bounds__(256) void k_edgem(
    const __hip_bfloat16* __restrict__ F, int ldf, int coff, int K,
    const __hip_bfloat16* __restrict__ Wl,  // [N][K] bf16
    const float* __restrict__ sc, const float* __restrict__ bi,
    const float* __restrict__ T, int N,
    const int* __restrict__ idx,
    float* __restrict__ outf, __hip_bfloat16* __restrict__ outb) {
  __shared__ __align__(16) char smem[320 * 66 * 2];  // 42240 B, overlaid stage/Ys
  __hip_bfloat16* Al = (__hip_bfloat16*)smem;              // 320*40
  __hip_bfloat16* Bl = (__hip_bfloat16*)(smem + 25600);    // 64*40
  __hip_bfloat16* Ys = (__hip_bfloat16*)smem;              // 320*66 (post-loop)
  const int tid = threadIdx.x, lane = tid & 63, wv = tid >> 6;
  const int blk = blockIdx.x, n0 = blockIdx.y * 64;
  const int arow = tid >> 2, akc = (tid & 3) * 8;
  const int fm = lane & 15, fq = lane >> 4;
  const __hip_bfloat16* ap[5];
#pragma unroll
  for (int l = 0; l < 5; ++l) {
    int row = arow + l * 64;
    int e = blk * 320 + row;
    int p = e / 20;
    int j = idx[(size_t)p * 20 + (e - p * 20)];
    int src = ((p >> 12) << 12) + j;
    ap[l] = F + (size_t)src * ldf + coff + akc;
  }
  f32x4 acc[5][4];
#pragma unroll
  for (int l = 0; l < 5; ++l)
#pragma unroll
    for (int nt = 0; nt < 4; ++nt) acc[l][nt] = (f32x4){0.f, 0.f, 0.f, 0.f};
  for (int c0 = 0; c0 < K; c0 += 32) {
#pragma unroll
    for (int l = 0; l < 5; ++l)
      *(float4*)&Al[(arow + l * 64) * 40 + akc] = *(const float4*)(ap[l] + c0);
    *(float4*)&Bl[arow * 40 + akc] = *(const float4*)(Wl + (size_t)(n0 + arow) * K + c0 + akc);
    __syncthreads();
    bf16x8 af[5], bfr[4];
#pragma unroll
    for (int l = 0; l < 5; ++l)
      af[l] = *(const bf16x8*)&Al[(wv * 80 + l * 16 + fm) * 40 + fq * 8];
#pragma unroll
    for (int nt = 0; nt < 4; ++nt)
      bfr[nt] = *(const bf16x8*)&Bl[(nt * 16 + fm) * 40 + fq * 8];
#pragma unroll
    for (int l = 0; l < 5; ++l)
#pragma unroll
      for (int nt = 0; nt < 4; ++nt)
        acc[l][nt] = __builtin_amdgcn_mfma_f32_16x16x32_bf16(af[l], bfr[nt], acc[l][nt], 0, 0, 0);
    __syncthreads();
  }
  // D frags -> Ys (bf16)
#pragma unroll
  for (int l = 0; l < 5; ++l)
#pragma unroll
    for (int nt = 0; nt < 4; ++nt)
#pragma unroll
      for (int r = 0; r < 4; ++r)
        Ys[(wv * 80 + l * 16 + fq * 4 + r) * 66 + nt * 16 + fm] = __float2bfloat16(acc[l][nt][r]);
  __syncthreads();
  // group-max over 20 edges + affine + lrelu: 16 groups x 64 cols
  const int col = tid & 63;
#pragma unroll
  for (int gi = 0; gi < 4; ++gi) {
    int grp = wv + gi * 4;
    float m = -INFINITY;
#pragma unroll
    for (int k = 0; k < 20; ++k)
      m = fmaxf(m, __bfloat162float(Ys[(grp * 20 + k) * 66 + col]));
    int p = blk * 16 + grp;
    int o = n0 + col;
    float v = lrelu((m + T[(size_t)p * N + o]) * sc[o] + bi[o]);
    outf[(size_t)p * 512 + o] = v;
    outb[(size_t)p * 512 + o] = __float2bfloat16(v);
  }
}

// ---------------- bias2: one wave per (b,o); b2g[b][o] = sum_c g[b][c]*Ws1[o][512+c] ----------------
__global__ __launch_bounds__(256) void k_bias2(const unsigned* __restrict__ gk,
                                               const float* __restrict__ Ws1,
                                               float* __restrict__ b2g) {
  const int lane = threadIdx.x & 63;
  const int wid = (blockIdx.x * 256 + threadIdx.x) >> 6;  // 0..1023
  const int b = wid >> 9, o = wid & 511;
  const float* wr = Ws1 + (size_t)o * 1536 + 512;
  const unsigned* g = gk + b * 1024;
  float acc = 0.f;
#pragma unroll
  for (int c = lane; c < 1024; c += 64) acc = fmaf(dekey(g[c]), wr[c], acc);
#pragma unroll
  for (int off = 32; off; off >>= 1) acc += __shfl_xor(acc, off, 64);
  if (lane == 0) b2g[b * 512 + o] = acc;
}

// ---------------- final head: out = H(8192x256) . Ws3^T + bs3 (fp32) ----------------
__global__ __launch_bounds__(256) void k_out(const float* __restrict__ H,
                                             const float* __restrict__ Ws3,
                                             const float* __restrict__ bs3,
                                             float* __restrict__ out) {
  __shared__ float Ws[13][256];
  const int tid = threadIdx.x;
  for (int e = tid; e < 13 * 256; e += 256) Ws[e >> 8][e & 255] = Ws3[e];
  __syncthreads();
  const int rloc = tid >> 4, o = tid & 15;
  const int row = blockIdx.x * 16 + rloc;
  if (o < 13) {
    const float* h = H + (size_t)row * 256;
    float acc = 0.f;
    for (int c = 0; c < 256; ++c) acc = fmaf(h[c], Ws[o][c], acc);
    out[(size_t)row * 13 + o] = acc + bs3[o];
  }
}

extern "C" void kernel_launch(void* const* d_in, const int* in_sizes, int n_in,
                              void* d_out, int out_size, void* d_ws, size_t ws_size,
                              hipStream_t stream) {
  const float* X   = (const float*)d_in[0];
  const float* W1  = (const float*)d_in[1];
  const float* S1  = (const float*)d_in[2];
  const float* B1  = (const float*)d_in[3];
  const float* W2  = (const float*)d_in[4];
  const float* S2  = (const float*)d_in[5];
  const float* B2  = (const float*)d_in[6];
  const float* W3  = (const float*)d_in[7];
  const float* S3  = (const float*)d_in[8];
  const float* B3  = (const float*)d_in[9];
  const float* W4  = (const float*)d_in[10];
  const float* S4  = (const float*)d_in[11];
  const float* B4  = (const float*)d_in[12];
  const float* Wg  = (const float*)d_in[13];
  const float* Sg  = (const float*)d_in[14];
  const float* Bg  = (const float*)d_in[15];
  const float* Ws1 = (const float*)d_in[16];
  const float* Ss1 = (const float*)d_in[17];
  const float* Bs1 = (const float*)d_in[18];
  const float* Ws2 = (const float*)d_in[19];
  const float* Ss2 = (const float*)d_in[20];
  const float* Bs2 = (const float*)d_in[21];
  const float* Ws3 = (const float*)d_in[22];
  const float* Bs3 = (const float*)d_in[23];

  char* ws = (char*)d_ws;
  // Workspace layout (~43 MB), lifetime-aliased region at the end.
  float*           xxb   = (float*)(ws + 0);            // 32 KB
  int*             idxb  = (int*)(ws + 32768);          // 640 KB
  unsigned*        gk    = (unsigned*)(ws + 688128);    // 8 KB
  float*           b2g   = (float*)(ws + 696320);       // 4 KB
  __hip_bfloat16*  Wgb   = (__hip_bfloat16*)(ws + 1048576);  // 1 MB
  __hip_bfloat16*  Ws1b  = (__hip_bfloat16*)(ws + 2097152);  // 512 KB
  __hip_bfloat16*  Ws2b  = (__hip_bfloat16*)(ws + 2621440);  // 256 KB
  __hip_bfloat16*  Wlb4  = (__hip_bfloat16*)(ws + 2883584);  // 64 KB
  __hip_bfloat16*  Wdb4  = (__hip_bfloat16*)(ws + 2949120);  // 64 KB
  __hip_bfloat16*  xcatb = (__hip_bfloat16*)(ws + 3145728);  // 8 MB
  float*           xcat  = (float*)(ws + 11534336);          // 16 MB
  char*            region = ws + 28311552;                   // 16 MB shared
  float*           dist  = (float*)(region);                  // kNN phase
  float*           Tbuf  = (float*)(region);                  // T / h2
  __hip_bfloat16*  h1b   = (__hip_bfloat16*)(region + 8388608);  // head phase

  hipMemsetAsync(gk, 0, 2 * 1024 * sizeof(unsigned), stream);

  // weight bf16 packs
  k_conv<<<dim3(256, 2), dim3(64), 0, stream>>>(W4, 256, 0, 0, 128, Wlb4);
  k_conv<<<dim3(256, 2), dim3(64), 0, stream>>>(W4, 256, 128, 1, 128, Wdb4);
  k_conv<<<dim3(1024, 8), dim3(64), 0, stream>>>(Wg, 512, 0, 0, 512, Wgb);
  k_conv<<<dim3(512, 8), dim3(64), 0, stream>>>(Ws1, 1536, 0, 0, 512, Ws1b);
  k_conv<<<dim3(256, 8), dim3(64), 0, stream>>>(Ws2, 512, 0, 0, 512, Ws2b);

  // ---- Layer 1 (C=3 -> 64) ----
  k_xx<<<dim3(2048), dim3(256), 0, stream>>>(X, 3, 3, xxb);
  for (int b = 0; b < 2; ++b)
    for (int c = 0; c < 4; ++c) {
      k_dist<<<dim3(16, 64), dim3(256), 0, stream>>>(X, 3, 3, xxb, dist, b, c * 1024);
      k_topk<<<dim3(256), dim3(256), 0, stream>>>(dist, idxb, b, c * 1024);
    }
  k_edge1<<<dim3(2048), dim3(256), 0, stream>>>(X, W1, S1, B1, idxb, xcat, xcatb);

  // ---- Layer 2 (64 -> 64), fp32 (feeds kNN) ----
  k_xx<<<dim3(2048), dim3(256), 0, stream>>>(xcat, 512, 64, xxb);
  for (int b = 0; b < 2; ++b)
    for (int c = 0; c < 4; ++c) {
      k_dist<<<dim3(16, 64), dim3(256), 0, stream>>>(xcat, 512, 64, xxb, dist, b, c * 1024);
      k_topk<<<dim3(256), dim3(256), 0, stream>>>(dist, idxb, b, c * 1024);
    }
  k_pwT<<<dim3(128, 1), dim3(256), 0, stream>>>(xcat, 512, 64, W2, 128, 64, Tbuf, 64);
  k_edge<<<dim3(2048, 1), dim3(256), 0, stream>>>(xcat, 512, 64, W2, S2, B2,
      idxb, Tbuf, 64, xcat + 64, xcatb + 64);

  // ---- Layer 3 (64 -> 128), fp32 (feeds kNN) ----
  k_xx<<<dim3(2048), dim3(256), 0, stream>>>(xcat + 64, 512, 64, xxb);
  for (int b = 0; b < 2; ++b)
    for (int c = 0; c < 4; ++c) {
      k_dist<<<dim3(16, 64), dim3(256), 0, stream>>>(xcat + 64, 512, 64, xxb, dist, b, c * 1024);
      k_topk<<<dim3(256), dim3(256), 0, stream>>>(dist, idxb, b, c * 1024);
    }
  k_pwT<<<dim3(128, 2), dim3(256), 0, stream>>>(xcat + 64, 512, 64, W3, 128, 64, Tbuf, 128);
  k_edge<<<dim3(2048, 2), dim3(256), 0, stream>>>(xcat + 64, 512, 64, W3, S3, B3,
      idxb, Tbuf, 128, xcat + 128, xcatb + 128);

  // ---- Layer 4 (128 -> 256), bf16 MFMA (x4 feeds nothing discrete) ----
  k_xx<<<dim3(2048), dim3(256), 0, stream>>>(xcat + 128, 512, 128, xxb);
  for (int b = 0; b < 2; ++b)
    for (int c = 0; c < 4; ++c) {
      k_dist<<<dim3(16, 64), dim3(256), 0, stream>>>(xcat + 128, 512, 128, xxb, dist, b, c * 1024);
      k_topk<<<dim3(256), dim3(256), 0, stream>>>(dist, idxb, b, c * 1024);
    }
  k_mm<0><<<dim3(64, 4), dim3(256), 0, stream>>>(xcatb + 128, 512, 128, Wdb4,
      nullptr, nullptr, nullptr, 256, Tbuf, 256, nullptr, 0, nullptr);
  k_edgem<<<dim3(512, 4), dim3(256), 0, stream>>>(xcatb, 512, 128, 128, Wlb4,
      S4, B4, Tbuf, 256, idxb, xcat + 256, xcatb + 256);

  // ---- head (all bf16 MFMA) ----
  k_mm<2><<<dim3(64, 16), dim3(256), 0, stream>>>(xcatb, 512, 512, Wgb,
      Sg, Bg, nullptr, 1024, nullptr, 0, nullptr, 0, gk);
  k_bias2<<<dim3(256), dim3(256), 0, stream>>>(gk, Ws1, b2g);
  k_mm<1><<<dim3(64, 8), dim3(256), 0, stream>>>(xcatb, 512, 512, Ws1b,
      Ss1, Bs1, b2g, 512, nullptr, 0, h1b, 512, nullptr);
  k_mm<1><<<dim3(64, 4), dim3(256), 0, stream>>>(h1b, 512, 512, Ws2b,
      Ss2, Bs2, nullptr, 256, Tbuf, 256, nullptr, 0, nullptr);
  k_out<<<dim3(512), dim3(256), 0, stream>>>(Tbuf, Ws3, Bs3, (float*)d_out);
}

// Round 5
// 1507.086 us; speedup vs baseline: 2.3975x; 1.9740x over previous
//
#include <hip/hip_runtime.h>
#include <hip/hip_bf16.h>

// DGCNN_Seg forward. B=2, N=4096, K=20. fp32 in/out; bf16 MFMA for layer-4 +
// head GEMMs; fp32 for kNN-feeding path (layers 1-3).
// Round 5: k_topk restructured — 1 block (4 waves) per row, 16-deep per-lane
// lists, per-wave extraction + tiny 4-way merge. Selection order unchanged.

#define DEVI static __device__ __forceinline__
typedef __attribute__((ext_vector_type(8))) short bf16x8;   // 8 bf16 = 4 VGPR
typedef __attribute__((ext_vector_type(4))) float f32x4;    // MFMA acc
typedef unsigned long long ull;

DEVI float lrelu(float y) { return y > 0.f ? y : 0.2f * y; }
DEVI unsigned okey(float f) {
  unsigned u = __float_as_uint(f);
  return (f < 0.f) ? ~u : (u | 0x80000000u);
}
DEVI float dekey(unsigned k) {
  return __uint_as_float((k & 0x80000000u) ? (k & 0x7fffffffu) : ~k);
}

// ---------------- weight fp32 -> bf16 pack: dst[o][c] = src[o*lds+off+c] (- src[o*lds+c] if sub)
__global__ __launch_bounds__(64) void k_conv(const float* __restrict__ src, int lds, int off,
                                             int sub, int Kc, __hip_bfloat16* __restrict__ dst) {
  int o = blockIdx.x, c = blockIdx.y * 64 + threadIdx.x;
  float v = src[(size_t)o * lds + off + c];
  if (sub) v -= src[(size_t)o * lds + c];
  dst[(size_t)o * Kc + c] = __float2bfloat16(v);
}

// ---------------- row squared-norms: one wave per row ----------------
__global__ __launch_bounds__(256) void k_xx(const float* __restrict__ F, int ldf, int C,
                                            float* __restrict__ xx) {
  int lane = threadIdx.x & 63;
  int row = blockIdx.x * 4 + (threadIdx.x >> 6);
  const float* f = F + (size_t)row * ldf;
  float s = 0.f;
  for (int c = lane; c < C; c += 64) { float v = f[c]; s += v * v; }
#pragma unroll
  for (int off = 32; off; off >>= 1) s += __shfl_xor(s, off, 64);
  if (lane == 0) xx[row] = s;
}

// ---------------- pairwise distances, 1024-row chunk (fp32; feeds kNN) ----------------
__global__ __launch_bounds__(256) void k_dist(const float* __restrict__ F, int ldf, int C,
                                              const float* __restrict__ xx,
                                              float* __restrict__ D, int b, int ibase) {
  __shared__ __align__(16) float As[16][64];
  __shared__ __align__(16) float Bs[16][64];
  const int tid = threadIdx.x;
  const int tx = tid & 15, ty = tid >> 4;
  const int i0 = ibase + blockIdx.x * 64, j0 = blockIdx.y * 64;
  const float* Fb = F + (size_t)b * 4096 * ldf;
  const int row = tid >> 2, q = (tid & 3) * 4;
  float acc[4][4] = {};
  for (int c0 = 0; c0 < C; c0 += 16) {
    if (C - c0 >= 16) {
      float4 a = *(const float4*)(Fb + (size_t)(i0 + row) * ldf + c0 + q);
      float4 w = *(const float4*)(Fb + (size_t)(j0 + row) * ldf + c0 + q);
      As[q + 0][row] = a.x; As[q + 1][row] = a.y; As[q + 2][row] = a.z; As[q + 3][row] = a.w;
      Bs[q + 0][row] = w.x; Bs[q + 1][row] = w.y; Bs[q + 2][row] = w.z; Bs[q + 3][row] = w.w;
    } else {
#pragma unroll
      for (int e = 0; e < 4; ++e) {
        int c = c0 + q + e;
        As[q + e][row] = (c < C) ? Fb[(size_t)(i0 + row) * ldf + c] : 0.f;
        Bs[q + e][row] = (c < C) ? Fb[(size_t)(j0 + row) * ldf + c] : 0.f;
      }
    }
    __syncthreads();
#pragma unroll
    for (int kk = 0; kk < 16; ++kk) {
      const float4 a4 = *(const float4*)&As[kk][ty * 4];
      const float4 b4 = *(const float4*)&Bs[kk][tx * 4];
      const float av[4] = {a4.x, a4.y, a4.z, a4.w};
      const float bv[4] = {b4.x, b4.y, b4.z, b4.w};
#pragma unroll
      for (int ii = 0; ii < 4; ++ii)
#pragma unroll
        for (int jj = 0; jj < 4; ++jj)
          acc[ii][jj] = fmaf(av[ii], bv[jj], acc[ii][jj]);
    }
    __syncthreads();
  }
  const float* xxb = xx + b * 4096;
#pragma unroll
  for (int ii = 0; ii < 4; ++ii) {
    int i = i0 + ty * 4 + ii;
    float xi = xxb[i];
#pragma unroll
    for (int jj = 0; jj < 4; ++jj) {
      int j = j0 + tx * 4 + jj;
      D[(size_t)(i - ibase) * 4096 + j] = xi + xxb[j] - 2.f * acc[ii][jj];
    }
  }
}

// ---------------- top-20 smallest per row: ONE BLOCK (4 waves) per row ----------------
// wave w scans cols [w*1024,(w+1)*1024) stride 64; per-lane sorted 16-list (exact:
// a lane sees exactly 16 candidates); per-wave 20-round argmin extraction -> LDS;
// lane 0 merges 4 sorted lists. Key order identical to previous rounds.
__global__ __launch_bounds__(256) void k_topk(const float* __restrict__ D,
                                              int* __restrict__ idx, int b, int ibase) {
  __shared__ ull cand[4][20];
  const int tid = threadIdx.x, lane = tid & 63, wv = tid >> 6;
  const int ir_ = blockIdx.x;
  const float* drow = D + (size_t)ir_ * 4096;
  ull arr[16];
#pragma unroll
  for (int t = 0; t < 16; ++t) arr[t] = ~0ull;
  const int base = wv * 1024 + lane;
#pragma unroll
  for (int it = 0; it < 16; ++it) {
    int j = base + it * 64;
    float d = drow[j];
    ull key = ((ull)okey(d) << 32) | (unsigned)j;
#pragma unroll
    for (int t = 15; t > 0; --t) {
      bool sh = key < arr[t - 1];
      ull c2 = sh ? arr[t - 1] : key;
      arr[t] = (c2 < arr[t]) ? c2 : arr[t];
    }
    arr[0] = (key < arr[0]) ? key : arr[0];
  }
  // wave-level extraction of 20 smallest
  for (int r = 0; r < 20; ++r) {
    ull h = arr[0];
#pragma unroll
    for (int off = 32; off; off >>= 1) {
      ull o = __shfl_xor(h, off, 64);
      h = (o < h) ? o : h;
    }
    if (lane == 0) cand[wv][r] = h;
    bool pop = (arr[0] == h);
#pragma unroll
    for (int t = 0; t < 15; ++t) arr[t] = pop ? arr[t + 1] : arr[t];
    arr[15] = pop ? ~0ull : arr[15];
  }
  __syncthreads();
  if (tid == 0) {
    int* op = idx + ((size_t)b * 4096 + ibase + ir_) * 20;
    int p0 = 0, p1 = 0, p2 = 0, p3 = 0;
    for (int r = 0; r < 20; ++r) {
      ull v0 = cand[0][p0], v1 = cand[1][p1], v2 = cand[2][p2], v3 = cand[3][p3];
      ull m01 = v0 < v1 ? v0 : v1;
      ull m23 = v2 < v3 ? v2 : v3;
      ull best = m01 < m23 ? m01 : m23;
      if (best == v0) ++p0; else if (best == v1) ++p1;
      else if (best == v2) ++p2; else ++p3;
      op[r] = (int)(best & 0xffffffffull);
      if (p0 > 19) p0 = 19;  // cand exhausted only when >20 picks from one list: impossible, guard anyway
      if (p1 > 19) p1 = 19;
      if (p2 > 19) p2 = 19;
      if (p3 > 19) p3 = 19;
    }
  }
}

// ---------------- EdgeConv layer 1 (fp32, Cin=3): one wave per point ----------------
__global__ __launch_bounds__(256) void k_edge1(const float* __restrict__ xf,
                                               const float* __restrict__ W1,
                                               const float* __restrict__ s1,
                                               const float* __restrict__ b1,
                                               const int* __restrict__ idx,
                                               float* __restrict__ xcat,
                                               __hip_bfloat16* __restrict__ xcatb) {
  const int lane = threadIdx.x & 63;
  const int p = blockIdx.x * 4 + (threadIdx.x >> 6);
  const int bb = p >> 12;
  float wl[3], wr[3];
#pragma unroll
  for (int c = 0; c < 3; ++c) {
    wl[c] = W1[lane * 6 + c];
    wr[c] = W1[lane * 6 + 3 + c];
  }
  const float s = s1[lane], bi = b1[lane];
  const float* xc = xf + (size_t)p * 3;
  const float x0 = xc[0], x1 = xc[1], x2 = xc[2];
  const float t = x0 * (wr[0] - wl[0]) + x1 * (wr[1] - wl[1]) + x2 * (wr[2] - wl[2]);
  const int* ir = idx + (size_t)p * 20;
  float best = -INFINITY;
  for (int k = 0; k < 20; ++k) {
    int j = ir[k];
    const float* xn = xf + ((size_t)(bb << 12) + j) * 3;
    float y = t + xn[0] * wl[0] + xn[1] * wl[1] + xn[2] * wl[2];
    y = lrelu(y * s + bi);
    best = fmaxf(best, y);
  }
  xcat[(size_t)p * 512 + lane] = best;
  xcatb[(size_t)p * 512 + lane] = __float2bfloat16(best);
}

// ---------------- fp32 pointwise GEMM, raw store (T for layers 2-3) ----------------
__global__ __launch_bounds__(256) void k_pwT(const float* __restrict__ A, int lda, int K,
                                             const float* __restrict__ W, int ldw, int wsub,
                                             float* __restrict__ out, int ldo) {
  __shared__ __align__(16) float As[16][64];
  __shared__ __align__(16) float Bs[16][64];
  const int tid = threadIdx.x;
  const int tx = tid & 15, ty = tid >> 4;
  const int i0 = blockIdx.x * 64, o0 = blockIdx.y * 64;
  const int row = tid >> 2, q = (tid & 3) * 4;
  float acc[4][4] = {};
  for (int c0 = 0; c0 < K; c0 += 16) {
    float4 a = *(const float4*)(A + (size_t)(i0 + row) * lda + c0 + q);
    As[q + 0][row] = a.x; As[q + 1][row] = a.y; As[q + 2][row] = a.z; As[q + 3][row] = a.w;
    const float* wp = W + (size_t)(o0 + row) * ldw + c0 + q;
#pragma unroll
    for (int e = 0; e < 4; ++e) Bs[q + e][row] = wp[wsub + e] - wp[e];
    __syncthreads();
#pragma unroll
    for (int kk = 0; kk < 16; ++kk) {
      const float4 a4 = *(const float4*)&As[kk][ty * 4];
      const float4 b4 = *(const float4*)&Bs[kk][tx * 4];
      const float av[4] = {a4.x, a4.y, a4.z, a4.w};
      const float bv[4] = {b4.x, b4.y, b4.z, b4.w};
#pragma unroll
      for (int ii = 0; ii < 4; ++ii)
#pragma unroll
        for (int jj = 0; jj < 4; ++jj)
          acc[ii][jj] = fmaf(av[ii], bv[jj], acc[ii][jj]);
    }
    __syncthreads();
  }
#pragma unroll
  for (int ii = 0; ii < 4; ++ii)
#pragma unroll
    for (int jj = 0; jj < 4; ++jj)
      out[(size_t)(i0 + ty * 4 + ii) * ldo + o0 + tx * 4 + jj] = acc[ii][jj];
}

// ---------------- fp32 EdgeConv GEMM (layers 2-3; feeds kNN, stays exact) ----------------
__global__ __launch_bounds__(256) void k_edge(const float* __restrict__ F, int ldf, int Cin,
                                              const float* __restrict__ W,
                                              const float* __restrict__ sc,
                                              const float* __restrict__ bi,
                                              const int* __restrict__ idx,
                                              const float* __restrict__ T, int ldt,
                                              float* __restrict__ out,
                                              __hip_bfloat16* __restrict__ outb) {
  __shared__ float As[16][80];
  __shared__ __align__(16) float Bs[16][64];
  __shared__ float Ys[80][64];
  const int tid = threadIdx.x;
  const int tx = tid & 15, ty = tid >> 4;
  const int r0 = blockIdx.x * 80;
  const int o0 = blockIdx.y * 64;
  const int ldw = 2 * Cin;
  int grow[5], gcol[5];
#pragma unroll
  for (int l = 0; l < 5; ++l) {
    int e = tid + l * 256;
    int rr = e >> 4;
    gcol[l] = e & 15;
    int gr = r0 + rr;
    int p = gr / 20;
    int j = idx[(size_t)p * 20 + (gr % 20)];
    grow[l] = ((p >> 12) << 12) + j;
  }
  float acc[5][4] = {};
  const int wrow = tid >> 2, wq = (tid & 3) * 4;
  for (int c0 = 0; c0 < Cin; c0 += 16) {
#pragma unroll
    for (int l = 0; l < 5; ++l) {
      int e = tid + l * 256;
      As[gcol[l]][e >> 4] = F[(size_t)grow[l] * ldf + c0 + gcol[l]];
    }
    {
      const float* wp = W + (size_t)(o0 + wrow) * ldw + c0 + wq;
#pragma unroll
      for (int e = 0; e < 4; ++e) Bs[wq + e][wrow] = wp[e];
    }
    __syncthreads();
#pragma unroll
    for (int kk = 0; kk < 16; ++kk) {
      float a[5];
#pragma unroll
      for (int l = 0; l < 5; ++l) a[l] = As[kk][ty + l * 16];
      const float4 b4 = *(const float4*)&Bs[kk][tx * 4];
      const float bv[4] = {b4.x, b4.y, b4.z, b4.w};
#pragma unroll
      for (int l = 0; l < 5; ++l)
#pragma unroll
        for (int jj = 0; jj < 4; ++jj)
          acc[l][jj] = fmaf(a[l], bv[jj], acc[l][jj]);
    }
    __syncthreads();
  }
#pragma unroll
  for (int l = 0; l < 5; ++l) {
    int r = ty + l * 16;
    int p = (r0 + r) / 20;
#pragma unroll
    for (int jj = 0; jj < 4; ++jj) {
      int o = o0 + tx * 4 + jj;
      float y = (acc[l][jj] + T[(size_t)p * ldt + o]) * sc[o] + bi[o];
      Ys[r][tx * 4 + jj] = lrelu(y);
    }
  }
  __syncthreads();
  const int grp = tid >> 6, col = tid & 63;
  float m = -INFINITY;
#pragma unroll
  for (int k = 0; k < 20; ++k) m = fmaxf(m, Ys[grp * 20 + k][col]);
  const int p = blockIdx.x * 4 + grp;
  out[(size_t)p * 512 + o0 + col] = m;
  outb[(size_t)p * 512 + o0 + col] = __float2bfloat16(m);
}

// ---------------- MFMA bf16 GEMM: block 128(M)x64(N), 4 waves x (32x64) ----------------
// EPI: 0=raw fp32 store, 1=lrelu((acc+extra)*s+b) -> outf/outb, 2=per-col max -> gmax atomic
template <int EPI>
__global__ __launch_bounds__(256) void k_mm(
    const __hip_bfloat16* __restrict__ A, int lda, int K,
    const __hip_bfloat16* __restrict__ B,  // [N][K] bf16
    const float* __restrict__ sc, const float* __restrict__ bi,
    const float* __restrict__ extra, int Ncols,
    float* __restrict__ outf, int ldof,
    __hip_bfloat16* __restrict__ outb, int ldob,
    unsigned* __restrict__ gmax) {
  __shared__ __align__(16) __hip_bfloat16 Al[128 * 40];
  __shared__ __align__(16) __hip_bfloat16 Bl[64 * 40];
  __shared__ float Red[4][64];
  const int tid = threadIdx.x, lane = tid & 63, wv = tid >> 6;
  const int m0 = blockIdx.x * 128, n0 = blockIdx.y * 64;
  const int arow = tid >> 2, akc = (tid & 3) * 8;
  const int fm = lane & 15, fq = lane >> 4;
  f32x4 acc[2][4];
#pragma unroll
  for (int mt = 0; mt < 2; ++mt)
#pragma unroll
    for (int nt = 0; nt < 4; ++nt) acc[mt][nt] = (f32x4){0.f, 0.f, 0.f, 0.f};
  for (int c0 = 0; c0 < K; c0 += 32) {
#pragma unroll
    for (int l = 0; l < 2; ++l) {
      int r = arow + l * 64;
      *(float4*)&Al[r * 40 + akc] = *(const float4*)(A + (size_t)(m0 + r) * lda + c0 + akc);
    }
    *(float4*)&Bl[arow * 40 + akc] = *(const float4*)(B + (size_t)(n0 + arow) * K + c0 + akc);
    __syncthreads();
    bf16x8 af[2], bfr[4];
#pragma unroll
    for (int mt = 0; mt < 2; ++mt)
      af[mt] = *(const bf16x8*)&Al[(wv * 32 + mt * 16 + fm) * 40 + fq * 8];
#pragma unroll
    for (int nt = 0; nt < 4; ++nt)
      bfr[nt] = *(const bf16x8*)&Bl[(nt * 16 + fm) * 40 + fq * 8];
#pragma unroll
    for (int mt = 0; mt < 2; ++mt)
#pragma unroll
      for (int nt = 0; nt < 4; ++nt)
        acc[mt][nt] = __builtin_amdgcn_mfma_f32_16x16x32_bf16(af[mt], bfr[nt], acc[mt][nt], 0, 0, 0);
    __syncthreads();
  }
  const int bidx = m0 >> 12;
  if (EPI == 0) {
#pragma unroll
    for (int mt = 0; mt < 2; ++mt)
#pragma unroll
      for (int nt = 0; nt < 4; ++nt)
#pragma unroll
        for (int r = 0; r < 4; ++r)
          outf[(size_t)(m0 + wv * 32 + mt * 16 + fq * 4 + r) * ldof + n0 + nt * 16 + fm] =
              acc[mt][nt][r];
  } else if (EPI == 1) {
#pragma unroll
    for (int nt = 0; nt < 4; ++nt) {
      int col = n0 + nt * 16 + fm;
      float s = sc[col], bb = bi[col];
      float ex = extra ? extra[bidx * Ncols + col] : 0.f;
#pragma unroll
      for (int mt = 0; mt < 2; ++mt)
#pragma unroll
        for (int r = 0; r < 4; ++r) {
          float v = lrelu((acc[mt][nt][r] + ex) * s + bb);
          size_t rr = (size_t)(m0 + wv * 32 + mt * 16 + fq * 4 + r);
          if (outf) outf[rr * ldof + col] = v;
          if (outb) outb[rr * ldob + col] = __float2bfloat16(v);
        }
    }
  } else {
#pragma unroll
    for (int nt = 0; nt < 4; ++nt) {
      int col = n0 + nt * 16 + fm;
      float s = sc[col], bb = bi[col];
      float m = -INFINITY;
#pragma unroll
      for (int mt = 0; mt < 2; ++mt)
#pragma unroll
        for (int r = 0; r < 4; ++r) m = fmaxf(m, lrelu(acc[mt][nt][r] * s + bb));
      m = fmaxf(m, __shfl_xor(m, 16, 64));
      m = fmaxf(m, __shfl_xor(m, 32, 64));
      if (fq == 0) Red[wv][nt * 16 + fm] = m;
    }
    __syncthreads();
    if (tid < 64) {
      float m = fmaxf(fmaxf(Red[0][tid], Red[1][tid]), fmaxf(Red[2][tid], Red[3][tid]));
      atomicMax(&gmax[bidx * Ncols + n0 + tid], okey(m));
    }
  }
}

// ---------------- MFMA bf16 EdgeConv (layer 4): 320 edges x 64 cols / block ----------------
__global__ __launch_bounds__(256) void k_edgem(
    const __hip_bfloat16* __restrict__ F, int ldf, int coff, int K,
    const __hip_bfloat16* __restrict__ Wl,  // [N][K] bf16
    const float* __restrict__ sc, const float* __restrict__ bi,
    const float* __restrict__ T, int N,
    const int* __restrict__ idx,
    float* __restrict__ outf, __hip_bfloat16* __restrict__ outb) {
  __shared__ __align__(16) char smem[320 * 66 * 2];  // 42240 B, overlaid stage/Ys
  __hip_bfloat16* Al = (__hip_bfloat16*)smem;              // 320*40
  __hip_bfloat16* Bl = (__hip_bfloat16*)(smem + 25600);    // 64*40
  __hip_bfloat16* Ys = (__hip_bfloat16*)smem;              // 320*66 (post-loop)
  const int tid = threadIdx.x, lane = tid & 63, wv = tid >> 6;
  const int blk = blockIdx.x, n0 = blockIdx.y * 64;
  const int arow = tid >> 2, akc = (tid & 3) * 8;
  const int fm = lane & 15, fq = lane >> 4;
  const __hip_bfloat16* ap[5];
#pragma unroll
  for (int l = 0; l < 5; ++l) {
    int row = arow + l * 64;
    int e = blk * 320 + row;
    int p = e / 20;
    int j = idx[(size_t)p * 20 + (e - p * 20)];
    int src = ((p >> 12) << 12) + j;
    ap[l] = F + (size_t)src * ldf + coff + akc;
  }
  f32x4 acc[5][4];
#pragma unroll
  for (int l = 0; l < 5; ++l)
#pragma unroll
    for (int nt = 0; nt < 4; ++nt) acc[l][nt] = (f32x4){0.f, 0.f, 0.f, 0.f};
  for (int c0 = 0; c0 < K; c0 += 32) {
#pragma unroll
    for (int l = 0; l < 5; ++l)
      *(float4*)&Al[(arow + l * 64) * 40 + akc] = *(const float4*)(ap[l] + c0);
    *(float4*)&Bl[arow * 40 + akc] = *(const float4*)(Wl + (size_t)(n0 + arow) * K + c0 + akc);
    __syncthreads();
    bf16x8 af[5], bfr[4];
#pragma unroll
    for (int l = 0; l < 5; ++l)
      af[l] = *(const bf16x8*)&Al[(wv * 80 + l * 16 + fm) * 40 + fq * 8];
#pragma unroll
    for (int nt = 0; nt < 4; ++nt)
      bfr[nt] = *(const bf16x8*)&Bl[(nt * 16 + fm) * 40 + fq * 8];
#pragma unroll
    for (int l = 0; l < 5; ++l)
#pragma unroll
      for (int nt = 0; nt < 4; ++nt)
        acc[l][nt] = __builtin_amdgcn_mfma_f32_16x16x32_bf16(af[l], bfr[nt], acc[l][nt], 0, 0, 0);
    __syncthreads();
  }
#pragma unroll
  for (int l = 0; l < 5; ++l)
#pragma unroll
    for (int nt = 0; nt < 4; ++nt)
#pragma unroll
      for (int r = 0; r < 4; ++r)
        Ys[(wv * 80 + l * 16 + fq * 4 + r) * 66 + nt * 16 + fm] = __float2bfloat16(acc[l][nt][r]);
  __syncthreads();
  const int col = tid & 63;
#pragma unroll
  for (int gi = 0; gi < 4; ++gi) {
    int grp = wv + gi * 4;
    float m = -INFINITY;
#pragma unroll
    for (int k = 0; k < 20; ++k)
      m = fmaxf(m, __bfloat162float(Ys[(grp * 20 + k) * 66 + col]));
    int p = blk * 16 + grp;
    int o = n0 + col;
    float v = lrelu((m + T[(size_t)p * N + o]) * sc[o] + bi[o]);
    outf[(size_t)p * 512 + o] = v;
    outb[(size_t)p * 512 + o] = __float2bfloat16(v);
  }
}

// ---------------- bias2: one wave per (b,o) ----------------
__global__ __launch_bounds__(256) void k_bias2(const unsigned* __restrict__ gk,
                                               const float* __restrict__ Ws1,
                                               float* __restrict__ b2g) {
  const int lane = threadIdx.x & 63;
  const int wid = (blockIdx.x * 256 + threadIdx.x) >> 6;  // 0..1023
  const int b = wid >> 9, o = wid & 511;
  const float* wr = Ws1 + (size_t)o * 1536 + 512;
  const unsigned* g = gk + b * 1024;
  float acc = 0.f;
#pragma unroll
  for (int c = lane; c < 1024; c += 64) acc = fmaf(dekey(g[c]), wr[c], acc);
#pragma unroll
  for (int off = 32; off; off >>= 1) acc += __shfl_xor(acc, off, 64);
  if (lane == 0) b2g[b * 512 + o] = acc;
}

// ---------------- final head: out = H(8192x256) . Ws3^T + bs3 (fp32) ----------------
__global__ __launch_bounds__(256) void k_out(const float* __restrict__ H,
                                             const float* __restrict__ Ws3,
                                             const float* __restrict__ bs3,
                                             float* __restrict__ out) {
  __shared__ float Ws[13][256];
  const int tid = threadIdx.x;
  for (int e = tid; e < 13 * 256; e += 256) Ws[e >> 8][e & 255] = Ws3[e];
  __syncthreads();
  const int rloc = tid >> 4, o = tid & 15;
  const int row = blockIdx.x * 16 + rloc;
  if (o < 13) {
    const float* h = H + (size_t)row * 256;
    float acc = 0.f;
    for (int c = 0; c < 256; ++c) acc = fmaf(h[c], Ws[o][c], acc);
    out[(size_t)row * 13 + o] = acc + bs3[o];
  }
}

extern "C" void kernel_launch(void* const* d_in, const int* in_sizes, int n_in,
                              void* d_out, int out_size, void* d_ws, size_t ws_size,
                              hipStream_t stream) {
  const float* X   = (const float*)d_in[0];
  const float* W1  = (const float*)d_in[1];
  const float* S1  = (const float*)d_in[2];
  const float* B1  = (const float*)d_in[3];
  const float* W2  = (const float*)d_in[4];
  const float* S2  = (const float*)d_in[5];
  const float* B2  = (const float*)d_in[6];
  const float* W3  = (const float*)d_in[7];
  const float* S3  = (const float*)d_in[8];
  const float* B3  = (const float*)d_in[9];
  const float* W4  = (const float*)d_in[10];
  const float* S4  = (const float*)d_in[11];
  const float* B4  = (const float*)d_in[12];
  const float* Wg  = (const float*)d_in[13];
  const float* Sg  = (const float*)d_in[14];
  const float* Bg  = (const float*)d_in[15];
  const float* Ws1 = (const float*)d_in[16];
  const float* Ss1 = (const float*)d_in[17];
  const float* Bs1 = (const float*)d_in[18];
  const float* Ws2 = (const float*)d_in[19];
  const float* Ss2 = (const float*)d_in[20];
  const float* Bs2 = (const float*)d_in[21];
  const float* Ws3 = (const float*)d_in[22];
  const float* Bs3 = (const float*)d_in[23];

  char* ws = (char*)d_ws;
  float*           xxb   = (float*)(ws + 0);            // 32 KB
  int*             idxb  = (int*)(ws + 32768);          // 640 KB
  unsigned*        gk    = (unsigned*)(ws + 688128);    // 8 KB
  float*           b2g   = (float*)(ws + 696320);       // 4 KB
  __hip_bfloat16*  Wgb   = (__hip_bfloat16*)(ws + 1048576);  // 1 MB
  __hip_bfloat16*  Ws1b  = (__hip_bfloat16*)(ws + 2097152);  // 512 KB
  __hip_bfloat16*  Ws2b  = (__hip_bfloat16*)(ws + 2621440);  // 256 KB
  __hip_bfloat16*  Wlb4  = (__hip_bfloat16*)(ws + 2883584);  // 64 KB
  __hip_bfloat16*  Wdb4  = (__hip_bfloat16*)(ws + 2949120);  // 64 KB
  __hip_bfloat16*  xcatb = (__hip_bfloat16*)(ws + 3145728);  // 8 MB
  float*           xcat  = (float*)(ws + 11534336);          // 16 MB
  char*            region = ws + 28311552;                   // 16 MB shared
  float*           dist  = (float*)(region);                  // kNN phase
  float*           Tbuf  = (float*)(region);                  // T / h2
  __hip_bfloat16*  h1b   = (__hip_bfloat16*)(region + 8388608);  // head phase

  hipMemsetAsync(gk, 0, 2 * 1024 * sizeof(unsigned), stream);

  // weight bf16 packs
  k_conv<<<dim3(256, 2), dim3(64), 0, stream>>>(W4, 256, 0, 0, 128, Wlb4);
  k_conv<<<dim3(256, 2), dim3(64), 0, stream>>>(W4, 256, 128, 1, 128, Wdb4);
  k_conv<<<dim3(1024, 8), dim3(64), 0, stream>>>(Wg, 512, 0, 0, 512, Wgb);
  k_conv<<<dim3(512, 8), dim3(64), 0, stream>>>(Ws1, 1536, 0, 0, 512, Ws1b);
  k_conv<<<dim3(256, 8), dim3(64), 0, stream>>>(Ws2, 512, 0, 0, 512, Ws2b);

  // ---- Layer 1 (C=3 -> 64) ----
  k_xx<<<dim3(2048), dim3(256), 0, stream>>>(X, 3, 3, xxb);
  for (int b = 0; b < 2; ++b)
    for (int c = 0; c < 4; ++c) {
      k_dist<<<dim3(16, 64), dim3(256), 0, stream>>>(X, 3, 3, xxb, dist, b, c * 1024);
      k_topk<<<dim3(1024), dim3(256), 0, stream>>>(dist, idxb, b, c * 1024);
    }
  k_edge1<<<dim3(2048), dim3(256), 0, stream>>>(X, W1, S1, B1, idxb, xcat, xcatb);

  // ---- Layer 2 (64 -> 64), fp32 (feeds kNN) ----
  k_xx<<<dim3(2048), dim3(256), 0, stream>>>(xcat, 512, 64, xxb);
  for (int b = 0; b < 2; ++b)
    for (int c = 0; c < 4; ++c) {
      k_dist<<<dim3(16, 64), dim3(256), 0, stream>>>(xcat, 512, 64, xxb, dist, b, c * 1024);
      k_topk<<<dim3(1024), dim3(256), 0, stream>>>(dist, idxb, b, c * 1024);
    }
  k_pwT<<<dim3(128, 1), dim3(256), 0, stream>>>(xcat, 512, 64, W2, 128, 64, Tbuf, 64);
  k_edge<<<dim3(2048, 1), dim3(256), 0, stream>>>(xcat, 512, 64, W2, S2, B2,
      idxb, Tbuf, 64, xcat + 64, xcatb + 64);

  // ---- Layer 3 (64 -> 128), fp32 (feeds kNN) ----
  k_xx<<<dim3(2048), dim3(256), 0, stream>>>(xcat + 64, 512, 64, xxb);
  for (int b = 0; b < 2; ++b)
    for (int c = 0; c < 4; ++c) {
      k_dist<<<dim3(16, 64), dim3(256), 0, stream>>>(xcat + 64, 512, 64, xxb, dist, b, c * 1024);
      k_topk<<<dim3(1024), dim3(256), 0, stream>>>(dist, idxb, b, c * 1024);
    }
  k_pwT<<<dim3(128, 2), dim3(256), 0, stream>>>(xcat + 64, 512, 64, W3, 128, 64, Tbuf, 128);
  k_edge<<<dim3(2048, 2), dim3(256), 0, stream>>>(xcat + 64, 512, 64, W3, S3, B3,
      idxb, Tbuf, 128, xcat + 128, xcatb + 128);

  // ---- Layer 4 (128 -> 256), bf16 MFMA ----
  k_xx<<<dim3(2048), dim3(256), 0, stream>>>(xcat + 128, 512, 128, xxb);
  for (int b = 0; b < 2; ++b)
    for (int c = 0; c < 4; ++c) {
      k_dist<<<dim3(16, 64), dim3(256), 0, stream>>>(xcat + 128, 512, 128, xxb, dist, b, c * 1024);
      k_topk<<<dim3(1024), dim3(256), 0, stream>>>(dist, idxb, b, c * 1024);
    }
  k_mm<0><<<dim3(64, 4), dim3(256), 0, stream>>>(xcatb + 128, 512, 128, Wdb4,
      nullptr, nullptr, nullptr, 256, Tbuf, 256, nullptr, 0, nullptr);
  k_edgem<<<dim3(512, 4), dim3(256), 0, stream>>>(xcatb, 512, 128, 128, Wlb4,
      S4, B4, Tbuf, 256, idxb, xcat + 256, xcatb + 256);

  // ---- head (all bf16 MFMA) ----
  k_mm<2><<<dim3(64, 16), dim3(256), 0, stream>>>(xcatb, 512, 512, Wgb,
      Sg, Bg, nullptr, 1024, nullptr, 0, nullptr, 0, gk);
  k_bias2<<<dim3(256), dim3(256), 0, stream>>>(gk, Ws1, b2g);
  k_mm<1><<<dim3(64, 8), dim3(256), 0, stream>>>(xcatb, 512, 512, Ws1b,
      Ss1, Bs1, b2g, 512, nullptr, 0, h1b, 512, nullptr);
  k_mm<1><<<dim3(64, 4), dim3(256), 0, stream>>>(h1b, 512, 512, Ws2b,
      Ss2, Bs2, nullptr, 256, Tbuf, 256, nullptr, 0, nullptr);
  k_out<<<dim3(512), dim3(256), 0, stream>>>(Tbuf, Ws3, Bs3, (float*)d_out);
}

// Round 6
// 1449.987 us; speedup vs baseline: 2.4919x; 1.0394x over previous
//
#include <hip/hip_runtime.h>
#include <hip/hip_bf16.h>

// DGCNN_Seg forward. B=2, N=4096, K=20. fp32 in/out; bf16 MFMA for layer-4 +
// head GEMMs; fp32 for kNN-feeding path (layers 1-3).
// Round 6: k_topk = bitonic-network sort + LDS extraction w/ 32-bit argmin;
// LDS bank-conflict padding in k_dist / k_pwT / k_edge.

#define DEVI static __device__ __forceinline__
typedef __attribute__((ext_vector_type(8))) short bf16x8;   // 8 bf16 = 4 VGPR
typedef __attribute__((ext_vector_type(4))) float f32x4;    // MFMA acc
typedef unsigned long long ull;

DEVI float lrelu(float y) { return y > 0.f ? y : 0.2f * y; }
DEVI unsigned okey(float f) {
  unsigned u = __float_as_uint(f);
  return (f < 0.f) ? ~u : (u | 0x80000000u);
}
DEVI float dekey(unsigned k) {
  return __uint_as_float((k & 0x80000000u) ? (k & 0x7fffffffu) : ~k);
}

// ---------------- weight fp32 -> bf16 pack ----------------
__global__ __launch_bounds__(64) void k_conv(const float* __restrict__ src, int lds, int off,
                                             int sub, int Kc, __hip_bfloat16* __restrict__ dst) {
  int o = blockIdx.x, c = blockIdx.y * 64 + threadIdx.x;
  float v = src[(size_t)o * lds + off + c];
  if (sub) v -= src[(size_t)o * lds + c];
  dst[(size_t)o * Kc + c] = __float2bfloat16(v);
}

// ---------------- row squared-norms: one wave per row ----------------
__global__ __launch_bounds__(256) void k_xx(const float* __restrict__ F, int ldf, int C,
                                            float* __restrict__ xx) {
  int lane = threadIdx.x & 63;
  int row = blockIdx.x * 4 + (threadIdx.x >> 6);
  const float* f = F + (size_t)row * ldf;
  float s = 0.f;
  for (int c = lane; c < C; c += 64) { float v = f[c]; s += v * v; }
#pragma unroll
  for (int off = 32; off; off >>= 1) s += __shfl_xor(s, off, 64);
  if (lane == 0) xx[row] = s;
}

// ---------------- pairwise distances, 1024-row chunk (fp32; feeds kNN) ----------------
// LDS rows padded 64->68 words: staging-write bank conflicts 4-way -> 2-way (free)
__global__ __launch_bounds__(256) void k_dist(const float* __restrict__ F, int ldf, int C,
                                              const float* __restrict__ xx,
                                              float* __restrict__ D, int b, int ibase) {
  __shared__ __align__(16) float As[16][68];
  __shared__ __align__(16) float Bs[16][68];
  const int tid = threadIdx.x;
  const int tx = tid & 15, ty = tid >> 4;
  const int i0 = ibase + blockIdx.x * 64, j0 = blockIdx.y * 64;
  const float* Fb = F + (size_t)b * 4096 * ldf;
  const int row = tid >> 2, q = (tid & 3) * 4;
  float acc[4][4] = {};
  for (int c0 = 0; c0 < C; c0 += 16) {
    if (C - c0 >= 16) {
      float4 a = *(const float4*)(Fb + (size_t)(i0 + row) * ldf + c0 + q);
      float4 w = *(const float4*)(Fb + (size_t)(j0 + row) * ldf + c0 + q);
      As[q + 0][row] = a.x; As[q + 1][row] = a.y; As[q + 2][row] = a.z; As[q + 3][row] = a.w;
      Bs[q + 0][row] = w.x; Bs[q + 1][row] = w.y; Bs[q + 2][row] = w.z; Bs[q + 3][row] = w.w;
    } else {
#pragma unroll
      for (int e = 0; e < 4; ++e) {
        int c = c0 + q + e;
        As[q + e][row] = (c < C) ? Fb[(size_t)(i0 + row) * ldf + c] : 0.f;
        Bs[q + e][row] = (c < C) ? Fb[(size_t)(j0 + row) * ldf + c] : 0.f;
      }
    }
    __syncthreads();
#pragma unroll
    for (int kk = 0; kk < 16; ++kk) {
      const float4 a4 = *(const float4*)&As[kk][ty * 4];
      const float4 b4 = *(const float4*)&Bs[kk][tx * 4];
      const float av[4] = {a4.x, a4.y, a4.z, a4.w};
      const float bv[4] = {b4.x, b4.y, b4.z, b4.w};
#pragma unroll
      for (int ii = 0; ii < 4; ++ii)
#pragma unroll
        for (int jj = 0; jj < 4; ++jj)
          acc[ii][jj] = fmaf(av[ii], bv[jj], acc[ii][jj]);
    }
    __syncthreads();
  }
  const float* xxb = xx + b * 4096;
#pragma unroll
  for (int ii = 0; ii < 4; ++ii) {
    int i = i0 + ty * 4 + ii;
    float xi = xxb[i];
#pragma unroll
    for (int jj = 0; jj < 4; ++jj) {
      int j = j0 + tx * 4 + jj;
      D[(size_t)(i - ibase) * 4096 + j] = xi + xxb[j] - 2.f * acc[ii][jj];
    }
  }
}

// ---------------- top-20 smallest per row: 1 block (4 waves) per row ----------------
// Per lane: 16 keys -> bitonic network sort (regs) -> spill to padded LDS.
// Extraction: 20 rounds of 32-bit hi/lo wave-min (okey then index), cur/nxt
// register prefetch hides LDS pop latency. Selection order identical to R5.
__global__ __launch_bounds__(256) void k_topk(const float* __restrict__ D,
                                              int* __restrict__ idx, int b, int ibase) {
  __shared__ ull sarr[4 * 64 * 17];  // per-lane sorted 16 (stride 17 u64: bank-spread)
  __shared__ ull cand[4][20];
  const int tid = threadIdx.x, lane = tid & 63, wv = tid >> 6;
  const int ir_ = blockIdx.x;
  const float* drow = D + (size_t)ir_ * 4096;
  ull arr[16];
  const int base = wv * 1024 + lane;
#pragma unroll
  for (int it = 0; it < 16; ++it) {
    int j = base + it * 64;
    float d = drow[j];
    arr[it] = ((ull)okey(d) << 32) | (unsigned)j;
  }
  // bitonic sort, ascending
#pragma unroll
  for (int k = 2; k <= 16; k <<= 1) {
#pragma unroll
    for (int jj = k >> 1; jj > 0; jj >>= 1) {
#pragma unroll
      for (int i = 0; i < 16; ++i) {
        int l = i ^ jj;
        if (l > i) {
          bool up = ((i & k) == 0);
          bool sw = (arr[i] > arr[l]) == up;
          ull a = arr[i], bb = arr[l];
          arr[i] = sw ? bb : a;
          arr[l] = sw ? a : bb;
        }
      }
    }
  }
  ull* myl = &sarr[(wv * 64 + lane) * 17];
#pragma unroll
  for (int t = 0; t < 16; ++t) myl[t] = arr[t];
  // extraction of wave top-20
  ull cur = arr[0], nxt = arr[1];
  int nidx = 2;
  for (int r = 0; r < 20; ++r) {
    unsigned hi = (unsigned)(cur >> 32), lo = (unsigned)cur;
    unsigned mh = hi;
#pragma unroll
    for (int off = 32; off; off >>= 1) {
      unsigned o = __shfl_xor(mh, off, 64);
      mh = o < mh ? o : mh;
    }
    unsigned lo2 = (hi == mh) ? lo : 0xFFFFFFFFu;
    unsigned ml = lo2;
#pragma unroll
    for (int off = 32; off; off >>= 1) {
      unsigned o = __shfl_xor(ml, off, 64);
      ml = o < ml ? o : ml;
    }
    if (lane == 0) cand[wv][r] = ((ull)mh << 32) | ml;
    bool pop = (hi == mh) && (lo == ml);
    if (pop) {
      cur = nxt;
      nxt = (nidx < 16) ? myl[nidx] : ~0ull;
      ++nidx;
    }
  }
  __syncthreads();
  if (tid == 0) {
    int* op = idx + ((size_t)b * 4096 + ibase + ir_) * 20;
    int p0 = 0, p1 = 0, p2 = 0, p3 = 0;
    for (int r = 0; r < 20; ++r) {
      ull v0 = cand[0][p0], v1 = cand[1][p1], v2 = cand[2][p2], v3 = cand[3][p3];
      ull m01 = v0 < v1 ? v0 : v1;
      ull m23 = v2 < v3 ? v2 : v3;
      ull best = m01 < m23 ? m01 : m23;
      if (best == v0) ++p0; else if (best == v1) ++p1;
      else if (best == v2) ++p2; else ++p3;
      op[r] = (int)(best & 0xffffffffull);
      if (p0 > 19) p0 = 19;
      if (p1 > 19) p1 = 19;
      if (p2 > 19) p2 = 19;
      if (p3 > 19) p3 = 19;
    }
  }
}

// ---------------- EdgeConv layer 1 (fp32, Cin=3): one wave per point ----------------
__global__ __launch_bounds__(256) void k_edge1(const float* __restrict__ xf,
                                               const float* __restrict__ W1,
                                               const float* __restrict__ s1,
                                               const float* __restrict__ b1,
                                               const int* __restrict__ idx,
                                               float* __restrict__ xcat,
                                               __hip_bfloat16* __restrict__ xcatb) {
  const int lane = threadIdx.x & 63;
  const int p = blockIdx.x * 4 + (threadIdx.x >> 6);
  const int bb = p >> 12;
  float wl[3], wr[3];
#pragma unroll
  for (int c = 0; c < 3; ++c) {
    wl[c] = W1[lane * 6 + c];
    wr[c] = W1[lane * 6 + 3 + c];
  }
  const float s = s1[lane], bi = b1[lane];
  const float* xc = xf + (size_t)p * 3;
  const float x0 = xc[0], x1 = xc[1], x2 = xc[2];
  const float t = x0 * (wr[0] - wl[0]) + x1 * (wr[1] - wl[1]) + x2 * (wr[2] - wl[2]);
  const int* ir = idx + (size_t)p * 20;
  float best = -INFINITY;
  for (int k = 0; k < 20; ++k) {
    int j = ir[k];
    const float* xn = xf + ((size_t)(bb << 12) + j) * 3;
    float y = t + xn[0] * wl[0] + xn[1] * wl[1] + xn[2] * wl[2];
    y = lrelu(y * s + bi);
    best = fmaxf(best, y);
  }
  xcat[(size_t)p * 512 + lane] = best;
  xcatb[(size_t)p * 512 + lane] = __float2bfloat16(best);
}

// ---------------- fp32 pointwise GEMM, raw store (T for layers 2-3) ----------------
__global__ __launch_bounds__(256) void k_pwT(const float* __restrict__ A, int lda, int K,
                                             const float* __restrict__ W, int ldw, int wsub,
                                             float* __restrict__ out, int ldo) {
  __shared__ __align__(16) float As[16][68];
  __shared__ __align__(16) float Bs[16][68];
  const int tid = threadIdx.x;
  const int tx = tid & 15, ty = tid >> 4;
  const int i0 = blockIdx.x * 64, o0 = blockIdx.y * 64;
  const int row = tid >> 2, q = (tid & 3) * 4;
  float acc[4][4] = {};
  for (int c0 = 0; c0 < K; c0 += 16) {
    float4 a = *(const float4*)(A + (size_t)(i0 + row) * lda + c0 + q);
    As[q + 0][row] = a.x; As[q + 1][row] = a.y; As[q + 2][row] = a.z; As[q + 3][row] = a.w;
    const float* wp = W + (size_t)(o0 + row) * ldw + c0 + q;
#pragma unroll
    for (int e = 0; e < 4; ++e) Bs[q + e][row] = wp[wsub + e] - wp[e];
    __syncthreads();
#pragma unroll
    for (int kk = 0; kk < 16; ++kk) {
      const float4 a4 = *(const float4*)&As[kk][ty * 4];
      const float4 b4 = *(const float4*)&Bs[kk][tx * 4];
      const float av[4] = {a4.x, a4.y, a4.z, a4.w};
      const float bv[4] = {b4.x, b4.y, b4.z, b4.w};
#pragma unroll
      for (int ii = 0; ii < 4; ++ii)
#pragma unroll
        for (int jj = 0; jj < 4; ++jj)
          acc[ii][jj] = fmaf(av[ii], bv[jj], acc[ii][jj]);
    }
    __syncthreads();
  }
#pragma unroll
  for (int ii = 0; ii < 4; ++ii)
#pragma unroll
    for (int jj = 0; jj < 4; ++jj)
      out[(size_t)(i0 + ty * 4 + ii) * ldo + o0 + tx * 4 + jj] = acc[ii][jj];
}

// ---------------- fp32 EdgeConv GEMM (layers 2-3; feeds kNN, stays exact) ----------------
// Padded LDS: As 80->81 (kills 16-way staging-write conflict), Bs 64->68, Ys 64->65
__global__ __launch_bounds__(256) void k_edge(const float* __restrict__ F, int ldf, int Cin,
                                              const float* __restrict__ W,
                                              const float* __restrict__ sc,
                                              const float* __restrict__ bi,
                                              const int* __restrict__ idx,
                                              const float* __restrict__ T, int ldt,
                                              float* __restrict__ out,
                                              __hip_bfloat16* __restrict__ outb) {
  __shared__ float As[16][81];
  __shared__ __align__(16) float Bs[16][68];
  __shared__ float Ys[80][65];
  const int tid = threadIdx.x;
  const int tx = tid & 15, ty = tid >> 4;
  const int r0 = blockIdx.x * 80;
  const int o0 = blockIdx.y * 64;
  const int ldw = 2 * Cin;
  int grow[5], gcol[5];
#pragma unroll
  for (int l = 0; l < 5; ++l) {
    int e = tid + l * 256;
    int rr = e >> 4;
    gcol[l] = e & 15;
    int gr = r0 + rr;
    int p = gr / 20;
    int j = idx[(size_t)p * 20 + (gr % 20)];
    grow[l] = ((p >> 12) << 12) + j;
  }
  float acc[5][4] = {};
  const int wrow = tid >> 2, wq = (tid & 3) * 4;
  for (int c0 = 0; c0 < Cin; c0 += 16) {
#pragma unroll
    for (int l = 0; l < 5; ++l) {
      int e = tid + l * 256;
      As[gcol[l]][e >> 4] = F[(size_t)grow[l] * ldf + c0 + gcol[l]];
    }
    {
      const float* wp = W + (size_t)(o0 + wrow) * ldw + c0 + wq;
#pragma unroll
      for (int e = 0; e < 4; ++e) Bs[wq + e][wrow] = wp[e];
    }
    __syncthreads();
#pragma unroll
    for (int kk = 0; kk < 16; ++kk) {
      float a[5];
#pragma unroll
      for (int l = 0; l < 5; ++l) a[l] = As[kk][ty + l * 16];
      const float4 b4 = *(const float4*)&Bs[kk][tx * 4];
      const float bv[4] = {b4.x, b4.y, b4.z, b4.w};
#pragma unroll
      for (int l = 0; l < 5; ++l)
#pragma unroll
        for (int jj = 0; jj < 4; ++jj)
          acc[l][jj] = fmaf(a[l], bv[jj], acc[l][jj]);
    }
    __syncthreads();
  }
#pragma unroll
  for (int l = 0; l < 5; ++l) {
    int r = ty + l * 16;
    int p = (r0 + r) / 20;
#pragma unroll
    for (int jj = 0; jj < 4; ++jj) {
      int o = o0 + tx * 4 + jj;
      float y = (acc[l][jj] + T[(size_t)p * ldt + o]) * sc[o] + bi[o];
      Ys[r][tx * 4 + jj] = lrelu(y);
    }
  }
  __syncthreads();
  const int grp = tid >> 6, col = tid & 63;
  float m = -INFINITY;
#pragma unroll
  for (int k = 0; k < 20; ++k) m = fmaxf(m, Ys[grp * 20 + k][col]);
  const int p = blockIdx.x * 4 + grp;
  out[(size_t)p * 512 + o0 + col] = m;
  outb[(size_t)p * 512 + o0 + col] = __float2bfloat16(m);
}

// ---------------- MFMA bf16 GEMM: block 128(M)x64(N), 4 waves x (32x64) ----------------
template <int EPI>
__global__ __launch_bounds__(256) void k_mm(
    const __hip_bfloat16* __restrict__ A, int lda, int K,
    const __hip_bfloat16* __restrict__ B,  // [N][K] bf16
    const float* __restrict__ sc, const float* __restrict__ bi,
    const float* __restrict__ extra, int Ncols,
    float* __restrict__ outf, int ldof,
    __hip_bfloat16* __restrict__ outb, int ldob,
    unsigned* __restrict__ gmax) {
  __shared__ __align__(16) __hip_bfloat16 Al[128 * 40];
  __shared__ __align__(16) __hip_bfloat16 Bl[64 * 40];
  __shared__ float Red[4][64];
  const int tid = threadIdx.x, lane = tid & 63, wv = tid >> 6;
  const int m0 = blockIdx.x * 128, n0 = blockIdx.y * 64;
  const int arow = tid >> 2, akc = (tid & 3) * 8;
  const int fm = lane & 15, fq = lane >> 4;
  f32x4 acc[2][4];
#pragma unroll
  for (int mt = 0; mt < 2; ++mt)
#pragma unroll
    for (int nt = 0; nt < 4; ++nt) acc[mt][nt] = (f32x4){0.f, 0.f, 0.f, 0.f};
  for (int c0 = 0; c0 < K; c0 += 32) {
#pragma unroll
    for (int l = 0; l < 2; ++l) {
      int r = arow + l * 64;
      *(float4*)&Al[r * 40 + akc] = *(const float4*)(A + (size_t)(m0 + r) * lda + c0 + akc);
    }
    *(float4*)&Bl[arow * 40 + akc] = *(const float4*)(B + (size_t)(n0 + arow) * K + c0 + akc);
    __syncthreads();
    bf16x8 af[2], bfr[4];
#pragma unroll
    for (int mt = 0; mt < 2; ++mt)
      af[mt] = *(const bf16x8*)&Al[(wv * 32 + mt * 16 + fm) * 40 + fq * 8];
#pragma unroll
    for (int nt = 0; nt < 4; ++nt)
      bfr[nt] = *(const bf16x8*)&Bl[(nt * 16 + fm) * 40 + fq * 8];
#pragma unroll
    for (int mt = 0; mt < 2; ++mt)
#pragma unroll
      for (int nt = 0; nt < 4; ++nt)
        acc[mt][nt] = __builtin_amdgcn_mfma_f32_16x16x32_bf16(af[mt], bfr[nt], acc[mt][nt], 0, 0, 0);
    __syncthreads();
  }
  const int bidx = m0 >> 12;
  if (EPI == 0) {
#pragma unroll
    for (int mt = 0; mt < 2; ++mt)
#pragma unroll
      for (int nt = 0; nt < 4; ++nt)
#pragma unroll
        for (int r = 0; r < 4; ++r)
          outf[(size_t)(m0 + wv * 32 + mt * 16 + fq * 4 + r) * ldof + n0 + nt * 16 + fm] =
              acc[mt][nt][r];
  } else if (EPI == 1) {
#pragma unroll
    for (int nt = 0; nt < 4; ++nt) {
      int col = n0 + nt * 16 + fm;
      float s = sc[col], bb = bi[col];
      float ex = extra ? extra[bidx * Ncols + col] : 0.f;
#pragma unroll
      for (int mt = 0; mt < 2; ++mt)
#pragma unroll
        for (int r = 0; r < 4; ++r) {
          float v = lrelu((acc[mt][nt][r] + ex) * s + bb);
          size_t rr = (size_t)(m0 + wv * 32 + mt * 16 + fq * 4 + r);
          if (outf) outf[rr * ldof + col] = v;
          if (outb) outb[rr * ldob + col] = __float2bfloat16(v);
        }
    }
  } else {
#pragma unroll
    for (int nt = 0; nt < 4; ++nt) {
      int col = n0 + nt * 16 + fm;
      float s = sc[col], bb = bi[col];
      float m = -INFINITY;
#pragma unroll
      for (int mt = 0; mt < 2; ++mt)
#pragma unroll
        for (int r = 0; r < 4; ++r) m = fmaxf(m, lrelu(acc[mt][nt][r] * s + bb));
      m = fmaxf(m, __shfl_xor(m, 16, 64));
      m = fmaxf(m, __shfl_xor(m, 32, 64));
      if (fq == 0) Red[wv][nt * 16 + fm] = m;
    }
    __syncthreads();
    if (tid < 64) {
      float m = fmaxf(fmaxf(Red[0][tid], Red[1][tid]), fmaxf(Red[2][tid], Red[3][tid]));
      atomicMax(&gmax[bidx * Ncols + n0 + tid], okey(m));
    }
  }
}

// ---------------- MFMA bf16 EdgeConv (layer 4): 320 edges x 64 cols / block ----------------
__global__ __launch_bounds__(256) void k_edgem(
    const __hip_bfloat16* __restrict__ F, int ldf, int coff, int K,
    const __hip_bfloat16* __restrict__ Wl,  // [N][K] bf16
    const float* __restrict__ sc, const float* __restrict__ bi,
    const float* __restrict__ T, int N,
    const int* __restrict__ idx,
    float* __restrict__ outf, __hip_bfloat16* __restrict__ outb) {
  __shared__ __align__(16) char smem[320 * 66 * 2];  // 42240 B, overlaid stage/Ys
  __hip_bfloat16* Al = (__hip_bfloat16*)smem;              // 320*40
  __hip_bfloat16* Bl = (__hip_bfloat16*)(smem + 25600);    // 64*40
  __hip_bfloat16* Ys = (__hip_bfloat16*)smem;              // 320*66 (post-loop)
  const int tid = threadIdx.x, lane = tid & 63, wv = tid >> 6;
  const int blk = blockIdx.x, n0 = blockIdx.y * 64;
  const int arow = tid >> 2, akc = (tid & 3) * 8;
  const int fm = lane & 15, fq = lane >> 4;
  const __hip_bfloat16* ap[5];
#pragma unroll
  for (int l = 0; l < 5; ++l) {
    int row = arow + l * 64;
    int e = blk * 320 + row;
    int p = e / 20;
    int j = idx[(size_t)p * 20 + (e - p * 20)];
    int src = ((p >> 12) << 12) + j;
    ap[l] = F + (size_t)src * ldf + coff + akc;
  }
  f32x4 acc[5][4];
#pragma unroll
  for (int l = 0; l < 5; ++l)
#pragma unroll
    for (int nt = 0; nt < 4; ++nt) acc[l][nt] = (f32x4){0.f, 0.f, 0.f, 0.f};
  for (int c0 = 0; c0 < K; c0 += 32) {
#pragma unroll
    for (int l = 0; l < 5; ++l)
      *(float4*)&Al[(arow + l * 64) * 40 + akc] = *(const float4*)(ap[l] + c0);
    *(float4*)&Bl[arow * 40 + akc] = *(const float4*)(Wl + (size_t)(n0 + arow) * K + c0 + akc);
    __syncthreads();
    bf16x8 af[5], bfr[4];
#pragma unroll
    for (int l = 0; l < 5; ++l)
      af[l] = *(const bf16x8*)&Al[(wv * 80 + l * 16 + fm) * 40 + fq * 8];
#pragma unroll
    for (int nt = 0; nt < 4; ++nt)
      bfr[nt] = *(const bf16x8*)&Bl[(nt * 16 + fm) * 40 + fq * 8];
#pragma unroll
    for (int l = 0; l < 5; ++l)
#pragma unroll
      for (int nt = 0; nt < 4; ++nt)
        acc[l][nt] = __builtin_amdgcn_mfma_f32_16x16x32_bf16(af[l], bfr[nt], acc[l][nt], 0, 0, 0);
    __syncthreads();
  }
#pragma unroll
  for (int l = 0; l < 5; ++l)
#pragma unroll
    for (int nt = 0; nt < 4; ++nt)
#pragma unroll
      for (int r = 0; r < 4; ++r)
        Ys[(wv * 80 + l * 16 + fq * 4 + r) * 66 + nt * 16 + fm] = __float2bfloat16(acc[l][nt][r]);
  __syncthreads();
  const int col = tid & 63;
#pragma unroll
  for (int gi = 0; gi < 4; ++gi) {
    int grp = wv + gi * 4;
    float m = -INFINITY;
#pragma unroll
    for (int k = 0; k < 20; ++k)
      m = fmaxf(m, __bfloat162float(Ys[(grp * 20 + k) * 66 + col]));
    int p = blk * 16 + grp;
    int o = n0 + col;
    float v = lrelu((m + T[(size_t)p * N + o]) * sc[o] + bi[o]);
    outf[(size_t)p * 512 + o] = v;
    outb[(size_t)p * 512 + o] = __float2bfloat16(v);
  }
}

// ---------------- bias2: one wave per (b,o) ----------------
__global__ __launch_bounds__(256) void k_bias2(const unsigned* __restrict__ gk,
                                               const float* __restrict__ Ws1,
                                               float* __restrict__ b2g) {
  const int lane = threadIdx.x & 63;
  const int wid = (blockIdx.x * 256 + threadIdx.x) >> 6;  // 0..1023
  const int b = wid >> 9, o = wid & 511;
  const float* wr = Ws1 + (size_t)o * 1536 + 512;
  const unsigned* g = gk + b * 1024;
  float acc = 0.f;
#pragma unroll
  for (int c = lane; c < 1024; c += 64) acc = fmaf(dekey(g[c]), wr[c], acc);
#pragma unroll
  for (int off = 32; off; off >>= 1) acc += __shfl_xor(acc, off, 64);
  if (lane == 0) b2g[b * 512 + o] = acc;
}

// ---------------- final head: out = H(8192x256) . Ws3^T + bs3 (fp32) ----------------
__global__ __launch_bounds__(256) void k_out(const float* __restrict__ H,
                                             const float* __restrict__ Ws3,
                                             const float* __restrict__ bs3,
                                             float* __restrict__ out) {
  __shared__ float Ws[13][256];
  const int tid = threadIdx.x;
  for (int e = tid; e < 13 * 256; e += 256) Ws[e >> 8][e & 255] = Ws3[e];
  __syncthreads();
  const int rloc = tid >> 4, o = tid & 15;
  const int row = blockIdx.x * 16 + rloc;
  if (o < 13) {
    const float* h = H + (size_t)row * 256;
    float acc = 0.f;
    for (int c = 0; c < 256; ++c) acc = fmaf(h[c], Ws[o][c], acc);
    out[(size_t)row * 13 + o] = acc + bs3[o];
  }
}

extern "C" void kernel_launch(void* const* d_in, const int* in_sizes, int n_in,
                              void* d_out, int out_size, void* d_ws, size_t ws_size,
                              hipStream_t stream) {
  const float* X   = (const float*)d_in[0];
  const float* W1  = (const float*)d_in[1];
  const float* S1  = (const float*)d_in[2];
  const float* B1  = (const float*)d_in[3];
  const float* W2  = (const float*)d_in[4];
  const float* S2  = (const float*)d_in[5];
  const float* B2  = (const float*)d_in[6];
  const float* W3  = (const float*)d_in[7];
  const float* S3  = (const float*)d_in[8];
  const float* B3  = (const float*)d_in[9];
  const float* W4  = (const float*)d_in[10];
  const float* S4  = (const float*)d_in[11];
  const float* B4  = (const float*)d_in[12];
  const float* Wg  = (const float*)d_in[13];
  const float* Sg  = (const float*)d_in[14];
  const float* Bg  = (const float*)d_in[15];
  const float* Ws1 = (const float*)d_in[16];
  const float* Ss1 = (const float*)d_in[17];
  const float* Bs1 = (const float*)d_in[18];
  const float* Ws2 = (const float*)d_in[19];
  const float* Ss2 = (const float*)d_in[20];
  const float* Bs2 = (const float*)d_in[21];
  const float* Ws3 = (const float*)d_in[22];
  const float* Bs3 = (const float*)d_in[23];

  char* ws = (char*)d_ws;
  float*           xxb   = (float*)(ws + 0);            // 32 KB
  int*             idxb  = (int*)(ws + 32768);          // 640 KB
  unsigned*        gk    = (unsigned*)(ws + 688128);    // 8 KB
  float*           b2g   = (float*)(ws + 696320);       // 4 KB
  __hip_bfloat16*  Wgb   = (__hip_bfloat16*)(ws + 1048576);  // 1 MB
  __hip_bfloat16*  Ws1b  = (__hip_bfloat16*)(ws + 2097152);  // 512 KB
  __hip_bfloat16*  Ws2b  = (__hip_bfloat16*)(ws + 2621440);  // 256 KB
  __hip_bfloat16*  Wlb4  = (__hip_bfloat16*)(ws + 2883584);  // 64 KB
  __hip_bfloat16*  Wdb4  = (__hip_bfloat16*)(ws + 2949120);  // 64 KB
  __hip_bfloat16*  xcatb = (__hip_bfloat16*)(ws + 3145728);  // 8 MB
  float*           xcat  = (float*)(ws + 11534336);          // 16 MB
  char*            region = ws + 28311552;                   // 16 MB shared
  float*           dist  = (float*)(region);                  // kNN phase
  float*           Tbuf  = (float*)(region);                  // T / h2
  __hip_bfloat16*  h1b   = (__hip_bfloat16*)(region + 8388608);  // head phase

  hipMemsetAsync(gk, 0, 2 * 1024 * sizeof(unsigned), stream);

  // weight bf16 packs
  k_conv<<<dim3(256, 2), dim3(64), 0, stream>>>(W4, 256, 0, 0, 128, Wlb4);
  k_conv<<<dim3(256, 2), dim3(64), 0, stream>>>(W4, 256, 128, 1, 128, Wdb4);
  k_conv<<<dim3(1024, 8), dim3(64), 0, stream>>>(Wg, 512, 0, 0, 512, Wgb);
  k_conv<<<dim3(512, 8), dim3(64), 0, stream>>>(Ws1, 1536, 0, 0, 512, Ws1b);
  k_conv<<<dim3(256, 8), dim3(64), 0, stream>>>(Ws2, 512, 0, 0, 512, Ws2b);

  // ---- Layer 1 (C=3 -> 64) ----
  k_xx<<<dim3(2048), dim3(256), 0, stream>>>(X, 3, 3, xxb);
  for (int b = 0; b < 2; ++b)
    for (int c = 0; c < 4; ++c) {
      k_dist<<<dim3(16, 64), dim3(256), 0, stream>>>(X, 3, 3, xxb, dist, b, c * 1024);
      k_topk<<<dim3(1024), dim3(256), 0, stream>>>(dist, idxb, b, c * 1024);
    }
  k_edge1<<<dim3(2048), dim3(256), 0, stream>>>(X, W1, S1, B1, idxb, xcat, xcatb);

  // ---- Layer 2 (64 -> 64), fp32 (feeds kNN) ----
  k_xx<<<dim3(2048), dim3(256), 0, stream>>>(xcat, 512, 64, xxb);
  for (int b = 0; b < 2; ++b)
    for (int c = 0; c < 4; ++c) {
      k_dist<<<dim3(16, 64), dim3(256), 0, stream>>>(xcat, 512, 64, xxb, dist, b, c * 1024);
      k_topk<<<dim3(1024), dim3(256), 0, stream>>>(dist, idxb, b, c * 1024);
    }
  k_pwT<<<dim3(128, 1), dim3(256), 0, stream>>>(xcat, 512, 64, W2, 128, 64, Tbuf, 64);
  k_edge<<<dim3(2048, 1), dim3(256), 0, stream>>>(xcat, 512, 64, W2, S2, B2,
      idxb, Tbuf, 64, xcat + 64, xcatb + 64);

  // ---- Layer 3 (64 -> 128), fp32 (feeds kNN) ----
  k_xx<<<dim3(2048), dim3(256), 0, stream>>>(xcat + 64, 512, 64, xxb);
  for (int b = 0; b < 2; ++b)
    for (int c = 0; c < 4; ++c) {
      k_dist<<<dim3(16, 64), dim3(256), 0, stream>>>(xcat + 64, 512, 64, xxb, dist, b, c * 1024);
      k_topk<<<dim3(1024), dim3(256), 0, stream>>>(dist, idxb, b, c * 1024);
    }
  k_pwT<<<dim3(128, 2), dim3(256), 0, stream>>>(xcat + 64, 512, 64, W3, 128, 64, Tbuf, 128);
  k_edge<<<dim3(2048, 2), dim3(256), 0, stream>>>(xcat + 64, 512, 64, W3, S3, B3,
      idxb, Tbuf, 128, xcat + 128, xcatb + 128);

  // ---- Layer 4 (128 -> 256), bf16 MFMA ----
  k_xx<<<dim3(2048), dim3(256), 0, stream>>>(xcat + 128, 512, 128, xxb);
  for (int b = 0; b < 2; ++b)
    for (int c = 0; c < 4; ++c) {
      k_dist<<<dim3(16, 64), dim3(256), 0, stream>>>(xcat + 128, 512, 128, xxb, dist, b, c * 1024);
      k_topk<<<dim3(1024), dim3(256), 0, stream>>>(dist, idxb, b, c * 1024);
    }
  k_mm<0><<<dim3(64, 4), dim3(256), 0, stream>>>(xcatb + 128, 512, 128, Wdb4,
      nullptr, nullptr, nullptr, 256, Tbuf, 256, nullptr, 0, nullptr);
  k_edgem<<<dim3(512, 4), dim3(256), 0, stream>>>(xcatb, 512, 128, 128, Wlb4,
      S4, B4, Tbuf, 256, idxb, xcat + 256, xcatb + 256);

  // ---- head (all bf16 MFMA) ----
  k_mm<2><<<dim3(64, 16), dim3(256), 0, stream>>>(xcatb, 512, 512, Wgb,
      Sg, Bg, nullptr, 1024, nullptr, 0, nullptr, 0, gk);
  k_bias2<<<dim3(256), dim3(256), 0, stream>>>(gk, Ws1, b2g);
  k_mm<1><<<dim3(64, 8), dim3(256), 0, stream>>>(xcatb, 512, 512, Ws1b,
      Ss1, Bs1, b2g, 512, nullptr, 0, h1b, 512, nullptr);
  k_mm<1><<<dim3(64, 4), dim3(256), 0, stream>>>(h1b, 512, 512, Ws2b,
      Ss2, Bs2, nullptr, 256, Tbuf, 256, nullptr, 0, nullptr);
  k_out<<<dim3(512), dim3(256), 0, stream>>>(Tbuf, Ws3, Bs3, (float*)d_out);
}